// Round 1
// baseline (2450.022 us; speedup 1.0000x reference)
//
#include <hip/hip_runtime.h>
#include <hip/hip_bf16.h>

constexpr int N_NODES = 50000;
constexpr int N_EDGES = 800000;
constexpr int F_IN = 128;
constexpr int H1 = 64;
constexpr int HEADS = 4;
constexpr int D_H = 32;
constexpr int HOUT = HEADS * D_H;       // 128
constexpr int N_REL = 4;
constexpr int N_GRAPHS = 64;
constexpr int MBIG = H1 * (1 + N_REL);  // 320: [root | rel0..rel3]

// ---- monotonic float<->uint mapping for atomicMax on floats ----
__device__ __forceinline__ unsigned f2mono(float f) {
  unsigned u = __float_as_uint(f);
  return (u & 0x80000000u) ? ~u : (u | 0x80000000u);
}
__device__ __forceinline__ float mono2f(unsigned m) {
  unsigned u = (m & 0x80000000u) ? (m & 0x7FFFFFFFu) : ~m;
  return __uint_as_float(u);
}
constexpr unsigned MONO_NEG_INF = 0x007FFFFFu;  // f2mono(-inf)

__device__ __forceinline__ void atomAddF(float* p, float v) {
  unsafeAtomicAdd(p, v);  // hardware global_atomic_add_f32 on gfx950
}

// ---- build Wbig[128][320] = [W_root | W_rel[0] | ... | W_rel[3]] ----
__global__ __launch_bounds__(256) void build_wbig(const float* __restrict__ W_root,
                                                  const float* __restrict__ W_rel,
                                                  float* __restrict__ Wbig) {
  int i = blockIdx.x * 256 + threadIdx.x;
  if (i >= F_IN * MBIG) return;
  int k = i / MBIG, c = i % MBIG;
  float v;
  if (c < H1) v = W_root[k * H1 + c];
  else {
    int r = (c - H1) >> 6, cc = (c - H1) & 63;
    v = W_rel[((size_t)r * F_IN + k) * H1 + cc];
  }
  Wbig[i] = v;
}

// ---- generic tiled f32 GEMM: C[N,M] = A[N,K] @ B[K,M], K % 16 == 0 ----
__global__ __launch_bounds__(256) void gemm_f32(const float* __restrict__ A,
                                                const float* __restrict__ B,
                                                float* __restrict__ C,
                                                int N, int K, int M) {
  __shared__ float As[16][64];
  __shared__ float Bs[16][65];
  int tid = threadIdx.x;
  int tx = tid & 15, ty = tid >> 4;
  int rowBase = blockIdx.x * 64;
  int colBase = blockIdx.y * 64;
  float acc[4][4] = {};
  for (int k0 = 0; k0 < K; k0 += 16) {
    for (int i = tid; i < 64 * 16; i += 256) {
      int r = i >> 4, kk = i & 15;
      int gr = rowBase + r;
      As[kk][r] = (gr < N) ? A[(size_t)gr * K + k0 + kk] : 0.f;
    }
    for (int i = tid; i < 16 * 64; i += 256) {
      int kk = i >> 6, c = i & 63;
      int gc = colBase + c;
      Bs[kk][c] = (gc < M) ? B[(size_t)(k0 + kk) * M + gc] : 0.f;
    }
    __syncthreads();
#pragma unroll
    for (int kk = 0; kk < 16; ++kk) {
      float a[4], b[4];
#pragma unroll
      for (int i = 0; i < 4; ++i) a[i] = As[kk][ty * 4 + i];
#pragma unroll
      for (int j = 0; j < 4; ++j) b[j] = Bs[kk][tx * 4 + j];
#pragma unroll
      for (int i = 0; i < 4; ++i)
#pragma unroll
        for (int j = 0; j < 4; ++j) acc[i][j] += a[i] * b[j];
    }
    __syncthreads();
  }
  for (int i = 0; i < 4; ++i) {
    int r = rowBase + ty * 4 + i;
    if (r >= N) break;
    for (int j = 0; j < 4; ++j) {
      int c = colBase + tx * 4 + j;
      if (c < M) C[(size_t)r * M + c] = acc[i][j];
    }
  }
}

// ---- RGCN: scatter pre-transformed messages (16 lanes/edge, float4 each) ----
__global__ __launch_bounds__(256) void rgcn_scatter(const float* __restrict__ xt,
                                                    const int* __restrict__ src,
                                                    const int* __restrict__ dst,
                                                    const int* __restrict__ etype,
                                                    float* __restrict__ acc,
                                                    float* __restrict__ cnt) {
  int t = blockIdx.x * 256 + threadIdx.x;
  int e = t >> 4, j = t & 15;
  if (e >= N_EDGES) return;
  int s = src[e], d = dst[e], r = etype[e];
  const float4 v = *reinterpret_cast<const float4*>(xt + (size_t)s * MBIG + H1 + r * H1 + j * 4);
  float* out = acc + ((size_t)d * N_REL + r) * H1 + j * 4;
  atomAddF(out + 0, v.x);
  atomAddF(out + 1, v.y);
  atomAddF(out + 2, v.z);
  atomAddF(out + 3, v.w);
  if (j == 0) atomAddF(cnt + (size_t)d * N_REL + r, 1.0f);
}

// ---- RGCN finish: h = relu(root + b + sum_r acc_r / max(cnt_r,1)) ----
__global__ __launch_bounds__(256) void rgcn_finish(const float* __restrict__ xt,
                                                   const float* __restrict__ acc,
                                                   const float* __restrict__ cnt,
                                                   const float* __restrict__ b_rgcn,
                                                   float* __restrict__ h) {
  int t = blockIdx.x * 256 + threadIdx.x;
  if (t >= N_NODES * H1) return;
  int n = t >> 6, c = t & 63;
  float v = xt[(size_t)n * MBIG + c] + b_rgcn[c];
#pragma unroll
  for (int r = 0; r < N_REL; ++r) {
    float ct = cnt[(size_t)n * N_REL + r];
    v += acc[((size_t)n * N_REL + r) * H1 + c] / fmaxf(ct, 1.0f);
  }
  h[t] = fmaxf(v, 0.f);
}

// ---- init mono buffers to -inf ----
__global__ __launch_bounds__(256) void init_mono(unsigned* __restrict__ p, int count) {
  int i = blockIdx.x * 256 + threadIdx.x;
  if (i < count) p[i] = MONO_NEG_INF;
}

// ---- per-node attention coefficients ----
__global__ __launch_bounds__(256) void gat_att(const float* __restrict__ g,
                                               const float* __restrict__ att_src,
                                               const float* __restrict__ att_dst,
                                               float* __restrict__ a_s,
                                               float* __restrict__ a_d) {
  int t = blockIdx.x * 256 + threadIdx.x;
  if (t >= N_NODES * HEADS) return;
  int n = t >> 2, hh = t & 3;
  const float* gp = g + (size_t)n * HOUT + hh * D_H;
  float s = 0.f, d = 0.f;
#pragma unroll
  for (int k = 0; k < D_H; ++k) {
    float gv = gp[k];
    s += gv * att_src[hh * D_H + k];
    d += gv * att_dst[hh * D_H + k];
  }
  a_s[t] = s;
  a_d[t] = d;
}

// ---- GAT edge pass 1: e = leaky(a_s[src]+a_d[dst], 0.2); segment max ----
__global__ __launch_bounds__(256) void gat_edge1(const float* __restrict__ a_s,
                                                 const float* __restrict__ a_d,
                                                 const int* __restrict__ src,
                                                 const int* __restrict__ dst,
                                                 float* __restrict__ e_val,
                                                 unsigned* __restrict__ m_mono) {
  int e = blockIdx.x * 256 + threadIdx.x;
  if (e >= N_EDGES) return;
  int s = src[e], d = dst[e];
  float4 as4 = *reinterpret_cast<const float4*>(a_s + (size_t)s * 4);
  float4 ad4 = *reinterpret_cast<const float4*>(a_d + (size_t)d * 4);
  float ev[4] = {as4.x + ad4.x, as4.y + ad4.y, as4.z + ad4.z, as4.w + ad4.w};
#pragma unroll
  for (int i = 0; i < 4; ++i) {
    float v = ev[i];
    v = (v > 0.f) ? v : 0.2f * v;
    ev[i] = v;
    atomicMax(m_mono + (size_t)d * 4 + i, f2mono(v));
  }
  *reinterpret_cast<float4*>(e_val + (size_t)e * 4) =
      make_float4(ev[0], ev[1], ev[2], ev[3]);
}

// ---- GAT edge pass 2+3 merged (32 lanes/edge): den += exp(e-m);
//      o[dst] += exp(e-m) * g[src]  (normalization by den deferred) ----
__global__ __launch_bounds__(256) void gat_edge23(const float* __restrict__ e_val,
                                                  const unsigned* __restrict__ m_mono,
                                                  const float* __restrict__ g,
                                                  const int* __restrict__ src,
                                                  const int* __restrict__ dst,
                                                  float* __restrict__ den,
                                                  float* __restrict__ o) {
  int t = blockIdx.x * 256 + threadIdx.x;
  int e = t >> 5, j = t & 31;
  if (e >= N_EDGES) return;
  int s = src[e], d = dst[e];
  int hh = j >> 3;
  float ev = e_val[(size_t)e * 4 + hh];
  float m = mono2f(m_mono[(size_t)d * 4 + hh]);
  float ex = __expf(ev - m);
  if (j < 4) {
    float ev2 = e_val[(size_t)e * 4 + j];
    float m2 = mono2f(m_mono[(size_t)d * 4 + j]);
    atomAddF(den + (size_t)d * 4 + j, __expf(ev2 - m2));
  }
  float4 gv = *reinterpret_cast<const float4*>(g + (size_t)s * HOUT + j * 4);
  float* op = o + (size_t)d * HOUT + j * 4;
  atomAddF(op + 0, ex * gv.x);
  atomAddF(op + 1, ex * gv.y);
  atomAddF(op + 2, ex * gv.z);
  atomAddF(op + 3, ex * gv.w);
}

// ---- head: o/den + b_gat -> leaky -> @W1+b1 -> leaky -> per-graph max ----
__global__ __launch_bounds__(256) void final_z(const float* __restrict__ o,
                                               const float* __restrict__ den,
                                               const float* __restrict__ b_gat,
                                               const float* __restrict__ W1,
                                               const float* __restrict__ b1,
                                               const int* __restrict__ batch,
                                               unsigned* __restrict__ p_mono) {
  __shared__ unsigned sp[N_GRAPHS * 16];
  for (int i = threadIdx.x; i < N_GRAPHS * 16; i += 256) sp[i] = MONO_NEG_INF;
  __syncthreads();
  int n = blockIdx.x * 256 + threadIdx.x;
  if (n < N_NODES) {
    float z[16];
#pragma unroll
    for (int j = 0; j < 16; ++j) z[j] = b1[j];
    float dinv[4];
#pragma unroll
    for (int r = 0; r < 4; ++r) {
      float dd = den[(size_t)n * 4 + r];
      dinv[r] = (dd > 0.f) ? (1.0f / dd) : 0.f;
    }
    for (int k = 0; k < HOUT; ++k) {
      float v = o[(size_t)n * HOUT + k] * dinv[k >> 5] + b_gat[k];
      v = (v > 0.f) ? v : 0.01f * v;
#pragma unroll
      for (int j = 0; j < 16; ++j) z[j] += v * W1[k * 16 + j];
    }
    int b = batch[n];
#pragma unroll
    for (int j = 0; j < 16; ++j) {
      float zz = z[j];
      zz = (zz > 0.f) ? zz : 0.01f * zz;
      atomicMax(&sp[b * 16 + j], f2mono(zz));
    }
  }
  __syncthreads();
  for (int i = threadIdx.x; i < N_GRAPHS * 16; i += 256) {
    unsigned v = sp[i];
    if (v != MONO_NEG_INF) atomicMax(p_mono + i, v);
  }
}

// ---- y = p @ W2 + b2 ----
__global__ void final_y(const unsigned* __restrict__ p_mono,
                        const float* __restrict__ W2,
                        const float* __restrict__ b2,
                        float* __restrict__ y) {
  int gr = threadIdx.x;
  if (gr >= N_GRAPHS) return;
  float acc = b2[0];
#pragma unroll
  for (int k = 0; k < 16; ++k) acc += mono2f(p_mono[gr * 16 + k]) * W2[k];
  y[gr] = acc;
}

extern "C" void kernel_launch(void* const* d_in, const int* in_sizes, int n_in,
                              void* d_out, int out_size, void* d_ws, size_t ws_size,
                              hipStream_t stream) {
  const float* x       = (const float*)d_in[0];
  const int*   eidx    = (const int*)d_in[1];
  const int*   etype   = (const int*)d_in[2];
  const int*   batch   = (const int*)d_in[3];
  const float* W_rel   = (const float*)d_in[4];
  const float* W_root  = (const float*)d_in[5];
  const float* b_rgcn  = (const float*)d_in[6];
  const float* W_gat   = (const float*)d_in[7];
  const float* att_src = (const float*)d_in[8];
  const float* att_dst = (const float*)d_in[9];
  const float* b_gat   = (const float*)d_in[10];
  const float* W1      = (const float*)d_in[11];
  const float* b1      = (const float*)d_in[12];
  const float* W2      = (const float*)d_in[13];
  const float* b2      = (const float*)d_in[14];
  float* y = (float*)d_out;

  const int* src = eidx;
  const int* dst = eidx + N_EDGES;

  float* ws = (float*)d_ws;
  // ---- workspace layout (float offsets); aggressive aliasing ----
  const size_t OFF_XT  = 0;          // 16,000,000  xt = x @ Wbig [N,320]
  const size_t OFF_G   = 0;          //  6,400,000  g (reuses xt)
  const size_t OFF_O   = 6400000;    //  6,400,000  o (reuses xt)
  const size_t OFF_ACC = 16000000;   // 12,800,000  RGCN acc [N,4,64]
  const size_t OFF_EV  = 16000000;   //  3,200,000  e_val (reuses acc)
  const size_t OFF_AS  = 19200000;   //    200,000  a_src (reuses acc)
  const size_t OFF_AD  = 19400000;   //    200,000  a_dst (reuses acc)
  const size_t OFF_DEN = 19600000;   //    200,000  softmax denom
  const size_t OFF_MM  = 19800000;   //    200,000  segment max (mono u32)
  const size_t OFF_PM  = 20000000;   //      1,024  pool max (mono u32)
  const size_t OFF_CNT = 28800000;   //    200,000  per-(node,rel) counts
  const size_t OFF_H   = 29000000;   //  3,200,000  h [N,64]
  const size_t OFF_WB  = 32200000;   //     40,960  Wbig
  const size_t TOTAL_F = 32240960;
  if (ws_size < TOTAL_F * sizeof(float)) return;  // insufficient workspace

  float* xt    = ws + OFF_XT;
  float* g     = ws + OFF_G;
  float* o     = ws + OFF_O;
  float* acc   = ws + OFF_ACC;
  float* ev    = ws + OFF_EV;
  float* a_s   = ws + OFF_AS;
  float* a_d   = ws + OFF_AD;
  float* den   = ws + OFF_DEN;
  unsigned* mm = (unsigned*)(ws + OFF_MM);
  float* cnt   = ws + OFF_CNT;
  float* h     = ws + OFF_H;
  float* wbig  = ws + OFF_WB;
  unsigned* pm = (unsigned*)(ws + OFF_PM);

  // 1. zero acc..cnt (contiguous 16,000,000..29,000,000)
  hipMemsetAsync(acc, 0, 13000000 * sizeof(float), stream);
  // 2. Wbig = [W_root | W_rel]
  build_wbig<<<(F_IN * MBIG + 255) / 256, 256, 0, stream>>>(W_root, W_rel, wbig);
  // 3. xt = x @ Wbig
  {
    dim3 grid((N_NODES + 63) / 64, (MBIG + 63) / 64);
    gemm_f32<<<grid, 256, 0, stream>>>(x, wbig, xt, N_NODES, F_IN, MBIG);
  }
  // 4. RGCN scatter
  rgcn_scatter<<<(N_EDGES * 16) / 256, 256, 0, stream>>>(xt, src, dst, etype, acc, cnt);
  // 5. RGCN finish -> h
  rgcn_finish<<<(N_NODES * H1 + 255) / 256, 256, 0, stream>>>(xt, acc, cnt, b_rgcn, h);
  // 6. zero o & den; init mono buffers (acc/xt regions now free)
  hipMemsetAsync(o, 0, 6400000 * sizeof(float), stream);
  hipMemsetAsync(den, 0, 200000 * sizeof(float), stream);
  init_mono<<<(200000 + 1024 + 255) / 256, 256, 0, stream>>>(mm, 200000 + 1024);
  // 7. g = h @ W_gat
  {
    dim3 grid((N_NODES + 63) / 64, (HOUT + 63) / 64);
    gemm_f32<<<grid, 256, 0, stream>>>(h, W_gat, g, N_NODES, H1, HOUT);
  }
  // 8. attention coefficients
  gat_att<<<(N_NODES * HEADS + 255) / 256, 256, 0, stream>>>(g, att_src, att_dst, a_s, a_d);
  // 9. GAT edge pass 1 (e + segment max)
  gat_edge1<<<(N_EDGES + 255) / 256, 256, 0, stream>>>(a_s, a_d, src, dst, ev, mm);
  // 10. GAT edge pass 2+3 (den + unnormalized o)
  gat_edge23<<<(N_EDGES * 32) / 256, 256, 0, stream>>>(ev, mm, g, src, dst, den, o);
  // 11. head + per-graph max pool
  final_z<<<(N_NODES + 255) / 256, 256, 0, stream>>>(o, den, b_gat, W1, b1, batch, pm);
  // 12. y = p @ W2 + b2
  final_y<<<1, 64, 0, stream>>>(pm, W2, b2, y);
}

// Round 2
// 574.231 us; speedup vs baseline: 4.2666x; 4.2666x over previous
//
#include <hip/hip_runtime.h>
#include <hip/hip_bf16.h>

constexpr int N_NODES = 50000;
constexpr int N_EDGES = 800000;
constexpr int F_IN = 128;
constexpr int H1 = 64;
constexpr int HEADS = 4;
constexpr int D_H = 32;
constexpr int HOUT = HEADS * D_H;       // 128
constexpr int N_REL = 4;
constexpr int N_GRAPHS = 64;
constexpr int MBIG = H1 * (1 + N_REL);  // 320: [root | rel0..rel3]

// ---- monotonic float<->uint mapping for atomicMax on floats ----
__device__ __forceinline__ unsigned f2mono(float f) {
  unsigned u = __float_as_uint(f);
  return (u & 0x80000000u) ? ~u : (u | 0x80000000u);
}
__device__ __forceinline__ float mono2f(unsigned m) {
  unsigned u = (m & 0x80000000u) ? (m & 0x7FFFFFFFu) : ~m;
  return __uint_as_float(u);
}
constexpr unsigned MONO_NEG_INF = 0x007FFFFFu;  // f2mono(-inf)

// ---- build Wbig[128][320] = [W_root | W_rel[0] | ... | W_rel[3]] ----
__global__ __launch_bounds__(256) void build_wbig(const float* __restrict__ W_root,
                                                  const float* __restrict__ W_rel,
                                                  float* __restrict__ Wbig) {
  int i = blockIdx.x * 256 + threadIdx.x;
  if (i >= F_IN * MBIG) return;
  int k = i / MBIG, c = i % MBIG;
  float v;
  if (c < H1) v = W_root[k * H1 + c];
  else {
    int r = (c - H1) >> 6, cc = (c - H1) & 63;
    v = W_rel[((size_t)r * F_IN + k) * H1 + cc];
  }
  Wbig[i] = v;
}

// ---- generic tiled f32 GEMM: C[N,M] = A[N,K] @ B[K,M], K % 16 == 0 ----
__global__ __launch_bounds__(256) void gemm_f32(const float* __restrict__ A,
                                                const float* __restrict__ B,
                                                float* __restrict__ C,
                                                int N, int K, int M) {
  __shared__ float As[16][64];
  __shared__ float Bs[16][65];
  int tid = threadIdx.x;
  int tx = tid & 15, ty = tid >> 4;
  int rowBase = blockIdx.x * 64;
  int colBase = blockIdx.y * 64;
  float acc[4][4] = {};
  for (int k0 = 0; k0 < K; k0 += 16) {
    for (int i = tid; i < 64 * 16; i += 256) {
      int r = i >> 4, kk = i & 15;
      int gr = rowBase + r;
      As[kk][r] = (gr < N) ? A[(size_t)gr * K + k0 + kk] : 0.f;
    }
    for (int i = tid; i < 16 * 64; i += 256) {
      int kk = i >> 6, c = i & 63;
      int gc = colBase + c;
      Bs[kk][c] = (gc < M) ? B[(size_t)(k0 + kk) * M + gc] : 0.f;
    }
    __syncthreads();
#pragma unroll
    for (int kk = 0; kk < 16; ++kk) {
      float a[4], b[4];
#pragma unroll
      for (int i = 0; i < 4; ++i) a[i] = As[kk][ty * 4 + i];
#pragma unroll
      for (int j = 0; j < 4; ++j) b[j] = Bs[kk][tx * 4 + j];
#pragma unroll
      for (int i = 0; i < 4; ++i)
#pragma unroll
        for (int j = 0; j < 4; ++j) acc[i][j] += a[i] * b[j];
    }
    __syncthreads();
  }
  for (int i = 0; i < 4; ++i) {
    int r = rowBase + ty * 4 + i;
    if (r >= N) break;
    for (int j = 0; j < 4; ++j) {
      int c = colBase + tx * 4 + j;
      if (c < M) C[(size_t)r * M + c] = acc[i][j];
    }
  }
}

// ---- CSR build: histogram of dst ----
__global__ __launch_bounds__(256) void k_hist(const int* __restrict__ dst,
                                              int* __restrict__ deg) {
  int e = blockIdx.x * 256 + threadIdx.x;
  if (e < N_EDGES) atomicAdd(&deg[dst[e]], 1);
}

// ---- CSR build: exclusive scan (single block, 1024 threads) ----
__global__ __launch_bounds__(1024) void k_scan(const int* __restrict__ deg,
                                               int* __restrict__ off,
                                               int* __restrict__ cursor) {
  __shared__ int sums[1024];
  int t = threadIdx.x;
  const int CH = (N_NODES + 1023) / 1024;  // 49
  int base = t * CH;
  int s = 0;
  for (int i = 0; i < CH; ++i) {
    int idx = base + i;
    if (idx < N_NODES) s += deg[idx];
  }
  sums[t] = s;
  __syncthreads();
  for (int d = 1; d < 1024; d <<= 1) {
    int v = (t >= d) ? sums[t - d] : 0;
    __syncthreads();
    sums[t] += v;
    __syncthreads();
  }
  int run = (t > 0) ? sums[t - 1] : 0;  // exclusive offset of this chunk
  for (int i = 0; i < CH; ++i) {
    int idx = base + i;
    if (idx < N_NODES) {
      int dg = deg[idx];
      off[idx] = run;
      cursor[idx] = run;
      run += dg;
    }
  }
  if (t == 1023) off[N_NODES] = sums[1023];
}

// ---- CSR build: fill packed (src | etype<<16) per slot ----
__global__ __launch_bounds__(256) void k_fill(const int* __restrict__ src,
                                              const int* __restrict__ dst,
                                              const int* __restrict__ etype,
                                              int* __restrict__ cursor,
                                              int* __restrict__ eprep) {
  int e = blockIdx.x * 256 + threadIdx.x;
  if (e >= N_EDGES) return;
  int pos = atomicAdd(&cursor[dst[e]], 1);
  eprep[pos] = src[e] | (etype[e] << 16);
}

// ---- RGCN: gather + mean + root + bias + relu, one wave per node ----
__global__ __launch_bounds__(256) void rgcn_gather(const float* __restrict__ xt,
                                                   const int* __restrict__ off,
                                                   const int* __restrict__ eprep,
                                                   const float* __restrict__ b_rgcn,
                                                   float* __restrict__ h) {
  int wid = (blockIdx.x * 256 + threadIdx.x) >> 6;  // node id (grid sized exactly)
  int lane = threadIdx.x & 63;
  int start = off[wid], end = off[wid + 1];
  float a0 = 0.f, a1 = 0.f, a2 = 0.f, a3 = 0.f;
  int c0 = 0, c1 = 0, c2 = 0, c3 = 0;
  for (int i = start; i < end; ++i) {
    int p = eprep[i];
    int s = p & 0xFFFF, r = p >> 16;
    float v = xt[(size_t)s * MBIG + H1 + (r << 6) + lane];
    a0 += (r == 0) ? v : 0.f;  c0 += (r == 0);
    a1 += (r == 1) ? v : 0.f;  c1 += (r == 1);
    a2 += (r == 2) ? v : 0.f;  c2 += (r == 2);
    a3 += (r == 3) ? v : 0.f;  c3 += (r == 3);
  }
  float v = xt[(size_t)wid * MBIG + lane] + b_rgcn[lane];
  v += a0 / (float)max(c0, 1);
  v += a1 / (float)max(c1, 1);
  v += a2 / (float)max(c2, 1);
  v += a3 / (float)max(c3, 1);
  h[(size_t)wid * H1 + lane] = fmaxf(v, 0.f);
}

// ---- per-node attention coefficients ----
__global__ __launch_bounds__(256) void gat_att(const float* __restrict__ g,
                                               const float* __restrict__ att_src,
                                               const float* __restrict__ att_dst,
                                               float* __restrict__ a_s,
                                               float* __restrict__ a_d) {
  int t = blockIdx.x * 256 + threadIdx.x;
  if (t >= N_NODES * HEADS) return;
  int n = t >> 2, hh = t & 3;
  const float* gp = g + (size_t)n * HOUT + hh * D_H;
  float s = 0.f, d = 0.f;
#pragma unroll
  for (int k = 0; k < D_H; ++k) {
    float gv = gp[k];
    s += gv * att_src[hh * D_H + k];
    d += gv * att_dst[hh * D_H + k];
  }
  a_s[t] = s;
  a_d[t] = d;
}

// ---- GAT: full softmax-attention aggregation, one wave per node ----
__global__ __launch_bounds__(256) void gat_gather(const float* __restrict__ g,
                                                  const float* __restrict__ a_s,
                                                  const float* __restrict__ a_d,
                                                  const int* __restrict__ off,
                                                  const int* __restrict__ eprep,
                                                  float* __restrict__ ebuf,
                                                  const float* __restrict__ b_gat,
                                                  float* __restrict__ o) {
  int wid = (blockIdx.x * 256 + threadIdx.x) >> 6;  // node id
  int lane = threadIdx.x & 63;
  int start = off[wid], end = off[wid + 1];
  float4 ad4 = *reinterpret_cast<const float4*>(a_d + (size_t)wid * 4);
  float m0 = -1e30f, m1 = -1e30f, m2 = -1e30f, m3 = -1e30f;
  // loop 1: lane-parallel edges — e = leaky(a_s[src]+a_d[n], 0.2), track max
  for (int i = start + lane; i < end; i += 64) {
    int p = eprep[i];
    int s = p & 0xFFFF;
    float4 as4 = *reinterpret_cast<const float4*>(a_s + (size_t)s * 4);
    float e0 = as4.x + ad4.x; e0 = (e0 > 0.f) ? e0 : 0.2f * e0;
    float e1 = as4.y + ad4.y; e1 = (e1 > 0.f) ? e1 : 0.2f * e1;
    float e2 = as4.z + ad4.z; e2 = (e2 > 0.f) ? e2 : 0.2f * e2;
    float e3 = as4.w + ad4.w; e3 = (e3 > 0.f) ? e3 : 0.2f * e3;
    m0 = fmaxf(m0, e0); m1 = fmaxf(m1, e1);
    m2 = fmaxf(m2, e2); m3 = fmaxf(m3, e3);
    *reinterpret_cast<float4*>(ebuf + (size_t)i * 4) = make_float4(e0, e1, e2, e3);
  }
  // wave-wide max per head
#pragma unroll
  for (int d = 1; d < 64; d <<= 1) {
    m0 = fmaxf(m0, __shfl_xor(m0, d));
    m1 = fmaxf(m1, __shfl_xor(m1, d));
    m2 = fmaxf(m2, __shfl_xor(m2, d));
    m3 = fmaxf(m3, __shfl_xor(m3, d));
  }
  int hh = lane >> 4;  // head owning channels 2*lane, 2*lane+1
  float mh = (hh == 0) ? m0 : (hh == 1) ? m1 : (hh == 2) ? m2 : m3;
  // loop 2: edge-serial, lane-parallel channels
  float ox = 0.f, oy = 0.f, den = 0.f;
  for (int i = start; i < end; ++i) {
    int p = eprep[i];
    int s = p & 0xFFFF;
    float e = ebuf[(size_t)i * 4 + hh];
    float ex = __expf(e - mh);
    den += ex;
    float2 gv = *reinterpret_cast<const float2*>(g + (size_t)s * HOUT + lane * 2);
    ox += ex * gv.x;
    oy += ex * gv.y;
  }
  float dinv = (den > 0.f) ? (1.0f / den) : 0.f;
  float2 bg = *reinterpret_cast<const float2*>(b_gat + lane * 2);
  float vx = ox * dinv + bg.x; vx = (vx > 0.f) ? vx : 0.01f * vx;
  float vy = oy * dinv + bg.y; vy = (vy > 0.f) ? vy : 0.01f * vy;
  *reinterpret_cast<float2*>(o + (size_t)wid * HOUT + lane * 2) = make_float2(vx, vy);
}

// ---- init mono buffer to -inf ----
__global__ __launch_bounds__(256) void init_mono(unsigned* __restrict__ p, int count) {
  int i = blockIdx.x * 256 + threadIdx.x;
  if (i < count) p[i] = MONO_NEG_INF;
}

// ---- head: z = leaky(o @ W1 + b1); per-graph max pool ----
__global__ __launch_bounds__(256) void final_z(const float* __restrict__ o,
                                               const float* __restrict__ W1,
                                               const float* __restrict__ b1,
                                               const int* __restrict__ batch,
                                               unsigned* __restrict__ p_mono) {
  __shared__ unsigned sp[N_GRAPHS * 16];
  for (int i = threadIdx.x; i < N_GRAPHS * 16; i += 256) sp[i] = MONO_NEG_INF;
  __syncthreads();
  int n = blockIdx.x * 256 + threadIdx.x;
  if (n < N_NODES) {
    float z[16];
#pragma unroll
    for (int j = 0; j < 16; ++j) z[j] = b1[j];
    for (int k = 0; k < HOUT; ++k) {
      float v = o[(size_t)n * HOUT + k];  // already normalized + bias + leaky
#pragma unroll
      for (int j = 0; j < 16; ++j) z[j] += v * W1[k * 16 + j];
    }
    int b = batch[n];
#pragma unroll
    for (int j = 0; j < 16; ++j) {
      float zz = z[j];
      zz = (zz > 0.f) ? zz : 0.01f * zz;
      atomicMax(&sp[b * 16 + j], f2mono(zz));
    }
  }
  __syncthreads();
  for (int i = threadIdx.x; i < N_GRAPHS * 16; i += 256) {
    unsigned v = sp[i];
    if (v != MONO_NEG_INF) atomicMax(p_mono + i, v);
  }
}

// ---- y = p @ W2 + b2 ----
__global__ void final_y(const unsigned* __restrict__ p_mono,
                        const float* __restrict__ W2,
                        const float* __restrict__ b2,
                        float* __restrict__ y) {
  int gr = threadIdx.x;
  if (gr >= N_GRAPHS) return;
  float acc = b2[0];
#pragma unroll
  for (int k = 0; k < 16; ++k) acc += mono2f(p_mono[gr * 16 + k]) * W2[k];
  y[gr] = acc;
}

extern "C" void kernel_launch(void* const* d_in, const int* in_sizes, int n_in,
                              void* d_out, int out_size, void* d_ws, size_t ws_size,
                              hipStream_t stream) {
  const float* x       = (const float*)d_in[0];
  const int*   eidx    = (const int*)d_in[1];
  const int*   etype   = (const int*)d_in[2];
  const int*   batch   = (const int*)d_in[3];
  const float* W_rel   = (const float*)d_in[4];
  const float* W_root  = (const float*)d_in[5];
  const float* b_rgcn  = (const float*)d_in[6];
  const float* W_gat   = (const float*)d_in[7];
  const float* att_src = (const float*)d_in[8];
  const float* att_dst = (const float*)d_in[9];
  const float* b_gat   = (const float*)d_in[10];
  const float* W1      = (const float*)d_in[11];
  const float* b1      = (const float*)d_in[12];
  const float* W2      = (const float*)d_in[13];
  const float* b2      = (const float*)d_in[14];
  float* y = (float*)d_out;

  const int* src = eidx;
  const int* dst = eidx + N_EDGES;

  float* ws = (float*)d_ws;
  // ---- workspace layout (float offsets) ----
  const size_t OFF_XT  = 0;           // 16,000,000  xt [N,320]
  const size_t OFF_G   = 0;           //  6,400,000  g (reuses xt after rgcn)
  const size_t OFF_O   = 6400000;     //  6,400,000  o
  const size_t OFF_EB  = 12800000;    //  3,200,000  ebuf [E,4]
  const size_t OFF_H   = 16000000;    //  3,200,000  h [N,64]
  const size_t OFF_AS  = 19200000;    //    200,000  a_src
  const size_t OFF_AD  = 19400000;    //    200,000  a_dst
  const size_t OFF_WB  = 19600000;    //     40,960  Wbig
  const size_t OFF_PM  = 19640960;    //      1,024  pool max (mono u32)
  const size_t OFF_DEG = 19642000;    //     50,000  deg (int)
  const size_t OFF_OFFS= 19692000;    //     50,001  off (int)
  const size_t OFF_CUR = 19742016;    //     50,000  cursor (int)
  const size_t OFF_EP  = 19792016;    //    800,000  eprep (int)
  const size_t TOTAL_F = 20592016;
  if (ws_size < TOTAL_F * sizeof(float)) return;

  float* xt    = ws + OFF_XT;
  float* g     = ws + OFF_G;
  float* o     = ws + OFF_O;
  float* ebuf  = ws + OFF_EB;
  float* h     = ws + OFF_H;
  float* a_s   = ws + OFF_AS;
  float* a_d   = ws + OFF_AD;
  float* wbig  = ws + OFF_WB;
  unsigned* pm = (unsigned*)(ws + OFF_PM);
  int* deg     = (int*)(ws + OFF_DEG);
  int* offs    = (int*)(ws + OFF_OFFS);
  int* cursor  = (int*)(ws + OFF_CUR);
  int* eprep   = (int*)(ws + OFF_EP);

  // CSR build (independent of GEMMs)
  hipMemsetAsync(deg, 0, N_NODES * sizeof(int), stream);
  k_hist<<<(N_EDGES + 255) / 256, 256, 0, stream>>>(dst, deg);
  k_scan<<<1, 1024, 0, stream>>>(deg, offs, cursor);
  k_fill<<<(N_EDGES + 255) / 256, 256, 0, stream>>>(src, dst, etype, cursor, eprep);

  // xt = x @ [W_root | W_rel]
  build_wbig<<<(F_IN * MBIG + 255) / 256, 256, 0, stream>>>(W_root, W_rel, wbig);
  {
    dim3 grid((N_NODES + 63) / 64, (MBIG + 63) / 64);
    gemm_f32<<<grid, 256, 0, stream>>>(x, wbig, xt, N_NODES, F_IN, MBIG);
  }

  // RGCN gather -> h  (one wave per node; grid exactly N_NODES waves)
  rgcn_gather<<<N_NODES / 4, 256, 0, stream>>>(xt, offs, eprep, b_rgcn, h);

  // g = h @ W_gat  (overwrites xt region — xt dead now)
  {
    dim3 grid((N_NODES + 63) / 64, (HOUT + 63) / 64);
    gemm_f32<<<grid, 256, 0, stream>>>(h, W_gat, g, N_NODES, H1, HOUT);
  }

  // attention coefficients
  gat_att<<<(N_NODES * HEADS + 255) / 256, 256, 0, stream>>>(g, att_src, att_dst, a_s, a_d);

  // GAT gather (softmax + aggregate + normalize + bias + leaky) -> o
  gat_gather<<<N_NODES / 4, 256, 0, stream>>>(g, a_s, a_d, offs, eprep, ebuf, b_gat, o);

  // head + per-graph max pool
  init_mono<<<(N_GRAPHS * 16 + 255) / 256, 256, 0, stream>>>(pm, N_GRAPHS * 16);
  final_z<<<(N_NODES + 255) / 256, 256, 0, stream>>>(o, W1, b1, batch, pm);
  final_y<<<1, 64, 0, stream>>>(pm, W2, b2, y);
}

// Round 3
// 401.488 us; speedup vs baseline: 6.1024x; 1.4303x over previous
//
#include <hip/hip_runtime.h>
#include <hip/hip_bf16.h>

constexpr int N_NODES = 50000;
constexpr int N_EDGES = 800000;
constexpr int F_IN = 128;
constexpr int H1 = 64;
constexpr int HEADS = 4;
constexpr int D_H = 32;
constexpr int HOUT = HEADS * D_H;       // 128
constexpr int N_REL = 4;
constexpr int N_GRAPHS = 64;
constexpr int MBIG = H1 * (1 + N_REL);  // 320: [root | rel0..rel3]
constexpr int NBLK = (N_NODES + 255) / 256;  // 196 scan blocks

// ---- monotonic float<->uint mapping for atomicMax on floats ----
__device__ __forceinline__ unsigned f2mono(float f) {
  unsigned u = __float_as_uint(f);
  return (u & 0x80000000u) ? ~u : (u | 0x80000000u);
}
__device__ __forceinline__ float mono2f(unsigned m) {
  unsigned u = (m & 0x80000000u) ? (m & 0x7FFFFFFFu) : ~m;
  return __uint_as_float(u);
}
constexpr unsigned MONO_NEG_INF = 0x007FFFFFu;

// ---- build Wbig[128][320] = [W_root | W_rel[0..3]] ----
__global__ __launch_bounds__(256) void build_wbig(const float* __restrict__ W_root,
                                                  const float* __restrict__ W_rel,
                                                  float* __restrict__ Wbig) {
  int i = blockIdx.x * 256 + threadIdx.x;
  if (i >= F_IN * MBIG) return;
  int k = i / MBIG, c = i % MBIG;
  float v;
  if (c < H1) v = W_root[k * H1 + c];
  else {
    int r = (c - H1) >> 6, cc = (c - H1) & 63;
    v = W_rel[((size_t)r * F_IN + k) * H1 + cc];
  }
  Wbig[i] = v;
}

// ---- tiled f32 GEMM v2: C[N,M] = A[N,K] @ B[K,M]; K%32==0, M%64==0 ----
// 128x64 tile, 256 threads, 8x4 outputs/thread, bank-padded LDS.
__global__ __launch_bounds__(256) void gemm_f32_v2(const float* __restrict__ A,
                                                   const float* __restrict__ B,
                                                   float* __restrict__ C,
                                                   int N, int K, int M) {
  __shared__ float As[128][33];  // [row][kk], stride 33: broadcast reads bank-split
  __shared__ float Bs[32][68];   // [kk][col], stride 68: float4 reads 2-way (free)
  int tid = threadIdx.x;
  int tx = tid & 15, ty = tid >> 4;
  int rowBase = blockIdx.x * 128;
  int colBase = blockIdx.y * 64;
  float acc[8][4] = {};
  for (int k0 = 0; k0 < K; k0 += 32) {
    // stage A tile: 128 rows x 32 k (float4 loads along k)
#pragma unroll
    for (int it = 0; it < 4; ++it) {
      int idx = it * 256 + tid;          // 0..1023 float4 slots
      int r = idx >> 3, kk4 = (idx & 7) * 4;
      int gr = rowBase + r;
      float4 v = make_float4(0.f, 0.f, 0.f, 0.f);
      if (gr < N) v = *reinterpret_cast<const float4*>(&A[(size_t)gr * K + k0 + kk4]);
      As[r][kk4 + 0] = v.x; As[r][kk4 + 1] = v.y;
      As[r][kk4 + 2] = v.z; As[r][kk4 + 3] = v.w;
    }
    // stage B tile: 32 k x 64 cols
#pragma unroll
    for (int it = 0; it < 2; ++it) {
      int idx = it * 256 + tid;          // 0..511 float4 slots
      int kk = idx >> 4, c4 = (idx & 15) * 4;
      float4 v = *reinterpret_cast<const float4*>(&B[(size_t)(k0 + kk) * M + colBase + c4]);
      *reinterpret_cast<float4*>(&Bs[kk][c4]) = v;
    }
    __syncthreads();
#pragma unroll
    for (int kk = 0; kk < 32; ++kk) {
      float4 b4 = *reinterpret_cast<const float4*>(&Bs[kk][tx * 4]);
#pragma unroll
      for (int i = 0; i < 8; ++i) {
        float a = As[ty * 8 + i][kk];
        acc[i][0] += a * b4.x; acc[i][1] += a * b4.y;
        acc[i][2] += a * b4.z; acc[i][3] += a * b4.w;
      }
    }
    __syncthreads();
  }
#pragma unroll
  for (int i = 0; i < 8; ++i) {
    int r = rowBase + ty * 8 + i;
    if (r < N) {
      float4 v = make_float4(acc[i][0], acc[i][1], acc[i][2], acc[i][3]);
      *reinterpret_cast<float4*>(&C[(size_t)r * M + colBase + tx * 4]) = v;
    }
  }
}

// ---- CSR build: histogram of dst ----
__global__ __launch_bounds__(256) void k_hist(const int* __restrict__ dst,
                                              int* __restrict__ deg) {
  int e = blockIdx.x * 256 + threadIdx.x;
  if (e < N_EDGES) atomicAdd(&deg[dst[e]], 1);
}

// ---- hierarchical scan stage 1: per-block sums of deg ----
__global__ __launch_bounds__(256) void k_s1(const int* __restrict__ deg,
                                            int* __restrict__ bsum) {
  __shared__ int ss[256];
  int t = threadIdx.x;
  int i = blockIdx.x * 256 + t;
  ss[t] = (i < N_NODES) ? deg[i] : 0;
  __syncthreads();
  for (int d = 128; d > 0; d >>= 1) {
    if (t < d) ss[t] += ss[t + d];
    __syncthreads();
  }
  if (t == 0) bsum[blockIdx.x] = ss[0];
}

// ---- scan stage 2: exclusive scan of 196 block sums (1 block) ----
__global__ __launch_bounds__(256) void k_s2(const int* __restrict__ bsum,
                                            int* __restrict__ bbase,
                                            int* __restrict__ off) {
  __shared__ int ss[256];
  int t = threadIdx.x;
  int v = (t < NBLK) ? bsum[t] : 0;
  ss[t] = v;
  __syncthreads();
  for (int d = 1; d < 256; d <<= 1) {
    int u = (t >= d) ? ss[t - d] : 0;
    __syncthreads();
    ss[t] += u;
    __syncthreads();
  }
  if (t < NBLK) bbase[t] = ss[t] - v;          // exclusive
  if (t == NBLK - 1) off[N_NODES] = ss[t];     // total
}

// ---- scan stage 3: block-local exclusive scan + base -> off, cursor ----
__global__ __launch_bounds__(256) void k_s3(const int* __restrict__ deg,
                                            const int* __restrict__ bbase,
                                            int* __restrict__ off,
                                            int* __restrict__ cursor) {
  __shared__ int ss[256];
  int t = threadIdx.x;
  int i = blockIdx.x * 256 + t;
  int v = (i < N_NODES) ? deg[i] : 0;
  ss[t] = v;
  __syncthreads();
  for (int d = 1; d < 256; d <<= 1) {
    int u = (t >= d) ? ss[t - d] : 0;
    __syncthreads();
    ss[t] += u;
    __syncthreads();
  }
  if (i < N_NODES) {
    int o = bbase[blockIdx.x] + ss[t] - v;
    off[i] = o;
    cursor[i] = o;
  }
}

// ---- CSR build: fill packed (src | etype<<16) per slot ----
__global__ __launch_bounds__(256) void k_fill(const int* __restrict__ src,
                                              const int* __restrict__ dst,
                                              const int* __restrict__ etype,
                                              int* __restrict__ cursor,
                                              int* __restrict__ eprep) {
  int e = blockIdx.x * 256 + threadIdx.x;
  if (e >= N_EDGES) return;
  int pos = atomicAdd(&cursor[dst[e]], 1);
  eprep[pos] = src[e] | (etype[e] << 16);
}

// ---- RGCN: gather + mean + root + bias + relu, one wave per node ----
__global__ __launch_bounds__(256) void rgcn_gather(const float* __restrict__ xt,
                                                   const int* __restrict__ off,
                                                   const int* __restrict__ eprep,
                                                   const float* __restrict__ b_rgcn,
                                                   float* __restrict__ h) {
  int wid = (blockIdx.x * 256 + threadIdx.x) >> 6;
  int lane = threadIdx.x & 63;
  int start = off[wid], end = off[wid + 1];
  float a0 = 0.f, a1 = 0.f, a2 = 0.f, a3 = 0.f;
  int c0 = 0, c1 = 0, c2 = 0, c3 = 0;
  for (int i = start; i < end; ++i) {
    int p = eprep[i];
    int s = p & 0xFFFF, r = p >> 16;
    float v = xt[(size_t)s * MBIG + H1 + (r << 6) + lane];
    a0 += (r == 0) ? v : 0.f;  c0 += (r == 0);
    a1 += (r == 1) ? v : 0.f;  c1 += (r == 1);
    a2 += (r == 2) ? v : 0.f;  c2 += (r == 2);
    a3 += (r == 3) ? v : 0.f;  c3 += (r == 3);
  }
  float v = xt[(size_t)wid * MBIG + lane] + b_rgcn[lane];
  v += a0 / (float)max(c0, 1);
  v += a1 / (float)max(c1, 1);
  v += a2 / (float)max(c2, 1);
  v += a3 / (float)max(c3, 1);
  h[(size_t)wid * H1 + lane] = fmaxf(v, 0.f);
}

// ---- attention coefficients: LDS-staged, 64 nodes/block ----
__global__ __launch_bounds__(256) void gat_att(const float* __restrict__ g,
                                               const float* __restrict__ att_src,
                                               const float* __restrict__ att_dst,
                                               float* __restrict__ a_s,
                                               float* __restrict__ a_d) {
  __shared__ float gs[64][129];
  __shared__ float asrc[HOUT], adst[HOUT];
  int t = threadIdx.x;
  if (t < HOUT) { asrc[t] = att_src[t]; adst[t] = att_dst[t]; }
  int nb = blockIdx.x * 64;
#pragma unroll
  for (int it = 0; it < 8; ++it) {
    int idx = it * 256 + t;             // 0..2047 float4 slots
    int r = idx >> 5, c4 = (idx & 31) * 4;
    int gn = nb + r;
    float4 v = make_float4(0.f, 0.f, 0.f, 0.f);
    if (gn < N_NODES) v = *reinterpret_cast<const float4*>(&g[(size_t)gn * HOUT + c4]);
    gs[r][c4 + 0] = v.x; gs[r][c4 + 1] = v.y;
    gs[r][c4 + 2] = v.z; gs[r][c4 + 3] = v.w;
  }
  __syncthreads();
  int n = t & 63, hh = t >> 6;          // wave-uniform head
  float s = 0.f, d = 0.f;
#pragma unroll
  for (int k = 0; k < D_H; ++k) {
    float gv = gs[n][hh * D_H + k];
    s += gv * asrc[hh * D_H + k];
    d += gv * adst[hh * D_H + k];
  }
  if (nb + n < N_NODES) {
    a_s[(size_t)(nb + n) * 4 + hh] = s;
    a_d[(size_t)(nb + n) * 4 + hh] = d;
  }
}

// ---- GAT: full softmax-attention aggregation, one wave per node ----
__global__ __launch_bounds__(256) void gat_gather(const float* __restrict__ g,
                                                  const float* __restrict__ a_s,
                                                  const float* __restrict__ a_d,
                                                  const int* __restrict__ off,
                                                  const int* __restrict__ eprep,
                                                  float* __restrict__ ebuf,
                                                  const float* __restrict__ b_gat,
                                                  float* __restrict__ o) {
  int wid = (blockIdx.x * 256 + threadIdx.x) >> 6;
  int lane = threadIdx.x & 63;
  int start = off[wid], end = off[wid + 1];
  float4 ad4 = *reinterpret_cast<const float4*>(a_d + (size_t)wid * 4);
  float m0 = -1e30f, m1 = -1e30f, m2 = -1e30f, m3 = -1e30f;
  for (int i = start + lane; i < end; i += 64) {
    int p = eprep[i];
    int s = p & 0xFFFF;
    float4 as4 = *reinterpret_cast<const float4*>(a_s + (size_t)s * 4);
    float e0 = as4.x + ad4.x; e0 = (e0 > 0.f) ? e0 : 0.2f * e0;
    float e1 = as4.y + ad4.y; e1 = (e1 > 0.f) ? e1 : 0.2f * e1;
    float e2 = as4.z + ad4.z; e2 = (e2 > 0.f) ? e2 : 0.2f * e2;
    float e3 = as4.w + ad4.w; e3 = (e3 > 0.f) ? e3 : 0.2f * e3;
    m0 = fmaxf(m0, e0); m1 = fmaxf(m1, e1);
    m2 = fmaxf(m2, e2); m3 = fmaxf(m3, e3);
    *reinterpret_cast<float4*>(ebuf + (size_t)i * 4) = make_float4(e0, e1, e2, e3);
  }
#pragma unroll
  for (int d = 1; d < 64; d <<= 1) {
    m0 = fmaxf(m0, __shfl_xor(m0, d));
    m1 = fmaxf(m1, __shfl_xor(m1, d));
    m2 = fmaxf(m2, __shfl_xor(m2, d));
    m3 = fmaxf(m3, __shfl_xor(m3, d));
  }
  int hh = lane >> 4;
  float mh = (hh == 0) ? m0 : (hh == 1) ? m1 : (hh == 2) ? m2 : m3;
  float ox = 0.f, oy = 0.f, den = 0.f;
  for (int i = start; i < end; ++i) {
    int p = eprep[i];
    int s = p & 0xFFFF;
    float e = ebuf[(size_t)i * 4 + hh];
    float ex = __expf(e - mh);
    den += ex;
    float2 gv = *reinterpret_cast<const float2*>(g + (size_t)s * HOUT + lane * 2);
    ox += ex * gv.x;
    oy += ex * gv.y;
  }
  float dinv = (den > 0.f) ? (1.0f / den) : 0.f;
  float2 bg = *reinterpret_cast<const float2*>(b_gat + lane * 2);
  float vx = ox * dinv + bg.x; vx = (vx > 0.f) ? vx : 0.01f * vx;
  float vy = oy * dinv + bg.y; vy = (vy > 0.f) ? vy : 0.01f * vy;
  *reinterpret_cast<float2*>(o + (size_t)wid * HOUT + lane * 2) = make_float2(vx, vy);
}

// ---- init mono buffer ----
__global__ __launch_bounds__(256) void init_mono(unsigned* __restrict__ p, int count) {
  int i = blockIdx.x * 256 + threadIdx.x;
  if (i < count) p[i] = MONO_NEG_INF;
}

// ---- head: z = leaky(o @ W1 + b1); per-graph max pool (LDS-staged) ----
__global__ __launch_bounds__(256) void final_z(const float* __restrict__ o,
                                               const float* __restrict__ W1,
                                               const float* __restrict__ b1,
                                               const int* __restrict__ batch,
                                               unsigned* __restrict__ p_mono) {
  __shared__ float os[64][129];
  __shared__ float w1s[HOUT * 16];
  __shared__ unsigned sp[N_GRAPHS * 16];
  int t = threadIdx.x;
  for (int i = t; i < N_GRAPHS * 16; i += 256) sp[i] = MONO_NEG_INF;
  for (int i = t; i < HOUT * 16; i += 256) w1s[i] = W1[i];
  int nb = blockIdx.x * 64;
#pragma unroll
  for (int it = 0; it < 8; ++it) {
    int idx = it * 256 + t;
    int r = idx >> 5, c4 = (idx & 31) * 4;
    int gn = nb + r;
    float4 v = make_float4(0.f, 0.f, 0.f, 0.f);
    if (gn < N_NODES) v = *reinterpret_cast<const float4*>(&o[(size_t)gn * HOUT + c4]);
    os[r][c4 + 0] = v.x; os[r][c4 + 1] = v.y;
    os[r][c4 + 2] = v.z; os[r][c4 + 3] = v.w;
  }
  __syncthreads();
  int n = t >> 2, jg = (t & 3) * 4;
  float z0 = b1[jg], z1 = b1[jg + 1], z2 = b1[jg + 2], z3 = b1[jg + 3];
#pragma unroll 8
  for (int k = 0; k < HOUT; ++k) {
    float v = os[n][k];
    float4 w = *reinterpret_cast<const float4*>(&w1s[k * 16 + jg]);
    z0 += v * w.x; z1 += v * w.y; z2 += v * w.z; z3 += v * w.w;
  }
  if (nb + n < N_NODES) {
    int b = batch[nb + n];
    float zz;
    zz = (z0 > 0.f) ? z0 : 0.01f * z0; atomicMax(&sp[b * 16 + jg + 0], f2mono(zz));
    zz = (z1 > 0.f) ? z1 : 0.01f * z1; atomicMax(&sp[b * 16 + jg + 1], f2mono(zz));
    zz = (z2 > 0.f) ? z2 : 0.01f * z2; atomicMax(&sp[b * 16 + jg + 2], f2mono(zz));
    zz = (z3 > 0.f) ? z3 : 0.01f * z3; atomicMax(&sp[b * 16 + jg + 3], f2mono(zz));
  }
  __syncthreads();
  for (int i = t; i < N_GRAPHS * 16; i += 256) {
    unsigned v = sp[i];
    if (v != MONO_NEG_INF) atomicMax(p_mono + i, v);
  }
}

// ---- y = p @ W2 + b2 ----
__global__ void final_y(const unsigned* __restrict__ p_mono,
                        const float* __restrict__ W2,
                        const float* __restrict__ b2,
                        float* __restrict__ y) {
  int gr = threadIdx.x;
  if (gr >= N_GRAPHS) return;
  float acc = b2[0];
#pragma unroll
  for (int k = 0; k < 16; ++k) acc += mono2f(p_mono[gr * 16 + k]) * W2[k];
  y[gr] = acc;
}

extern "C" void kernel_launch(void* const* d_in, const int* in_sizes, int n_in,
                              void* d_out, int out_size, void* d_ws, size_t ws_size,
                              hipStream_t stream) {
  const float* x       = (const float*)d_in[0];
  const int*   eidx    = (const int*)d_in[1];
  const int*   etype   = (const int*)d_in[2];
  const int*   batch   = (const int*)d_in[3];
  const float* W_rel   = (const float*)d_in[4];
  const float* W_root  = (const float*)d_in[5];
  const float* b_rgcn  = (const float*)d_in[6];
  const float* W_gat   = (const float*)d_in[7];
  const float* att_src = (const float*)d_in[8];
  const float* att_dst = (const float*)d_in[9];
  const float* b_gat   = (const float*)d_in[10];
  const float* W1      = (const float*)d_in[11];
  const float* b1      = (const float*)d_in[12];
  const float* W2      = (const float*)d_in[13];
  const float* b2      = (const float*)d_in[14];
  float* y = (float*)d_out;

  const int* src = eidx;
  const int* dst = eidx + N_EDGES;

  float* ws = (float*)d_ws;
  const size_t OFF_XT  = 0;           // 16,000,000  xt [N,320]
  const size_t OFF_G   = 0;           //  6,400,000  g (reuses xt after rgcn)
  const size_t OFF_O   = 6400000;     //  6,400,000  o
  const size_t OFF_EB  = 12800000;    //  3,200,000  ebuf [E,4]
  const size_t OFF_H   = 16000000;    //  3,200,000  h [N,64]
  const size_t OFF_AS  = 19200000;    //    200,000  a_src
  const size_t OFF_AD  = 19400000;    //    200,000  a_dst
  const size_t OFF_WB  = 19600000;    //     40,960  Wbig
  const size_t OFF_PM  = 19640960;    //      1,024  pool max (mono u32)
  const size_t OFF_DEG = 19642000;    //     50,000  deg (int)
  const size_t OFF_OFFS= 19692000;    //     50,001  off (int)
  const size_t OFF_CUR = 19742016;    //     50,000  cursor (int)
  const size_t OFF_EP  = 19792016;    //    800,000  eprep (int)
  const size_t OFF_BS  = 20592016;    //        196  block sums (int)
  const size_t OFF_BB  = 20592212;    //        196  block bases (int)
  const size_t TOTAL_F = 20592512;
  if (ws_size < TOTAL_F * sizeof(float)) return;

  float* xt    = ws + OFF_XT;
  float* g     = ws + OFF_G;
  float* o     = ws + OFF_O;
  float* ebuf  = ws + OFF_EB;
  float* h     = ws + OFF_H;
  float* a_s   = ws + OFF_AS;
  float* a_d   = ws + OFF_AD;
  float* wbig  = ws + OFF_WB;
  unsigned* pm = (unsigned*)(ws + OFF_PM);
  int* deg     = (int*)(ws + OFF_DEG);
  int* offs    = (int*)(ws + OFF_OFFS);
  int* cursor  = (int*)(ws + OFF_CUR);
  int* eprep   = (int*)(ws + OFF_EP);
  int* bsum    = (int*)(ws + OFF_BS);
  int* bbase   = (int*)(ws + OFF_BB);

  // CSR build
  hipMemsetAsync(deg, 0, N_NODES * sizeof(int), stream);
  k_hist<<<(N_EDGES + 255) / 256, 256, 0, stream>>>(dst, deg);
  k_s1<<<NBLK, 256, 0, stream>>>(deg, bsum);
  k_s2<<<1, 256, 0, stream>>>(bsum, bbase, offs);
  k_s3<<<NBLK, 256, 0, stream>>>(deg, bbase, offs, cursor);
  k_fill<<<(N_EDGES + 255) / 256, 256, 0, stream>>>(src, dst, etype, cursor, eprep);

  // xt = x @ [W_root | W_rel]
  build_wbig<<<(F_IN * MBIG + 255) / 256, 256, 0, stream>>>(W_root, W_rel, wbig);
  {
    dim3 grid((N_NODES + 127) / 128, MBIG / 64);
    gemm_f32_v2<<<grid, 256, 0, stream>>>(x, wbig, xt, N_NODES, F_IN, MBIG);
  }

  // RGCN gather -> h
  rgcn_gather<<<N_NODES / 4, 256, 0, stream>>>(xt, offs, eprep, b_rgcn, h);

  // g = h @ W_gat (overwrites xt region — xt dead now)
  {
    dim3 grid((N_NODES + 127) / 128, HOUT / 64);
    gemm_f32_v2<<<grid, 256, 0, stream>>>(h, W_gat, g, N_NODES, H1, HOUT);
  }

  // attention coefficients
  gat_att<<<(N_NODES + 63) / 64, 256, 0, stream>>>(g, att_src, att_dst, a_s, a_d);

  // GAT gather -> o (normalized + bias + leaky)
  gat_gather<<<N_NODES / 4, 256, 0, stream>>>(g, a_s, a_d, offs, eprep, ebuf, b_gat, o);

  // head + per-graph max pool
  init_mono<<<(N_GRAPHS * 16 + 255) / 256, 256, 0, stream>>>(pm, N_GRAPHS * 16);
  final_z<<<(N_NODES + 63) / 64, 256, 0, stream>>>(o, W1, b1, batch, pm);
  final_y<<<1, 64, 0, stream>>>(pm, W2, b2, y);
}

// Round 4
// 303.283 us; speedup vs baseline: 8.0783x; 1.3238x over previous
//
#include <hip/hip_runtime.h>
#include <hip/hip_bf16.h>

constexpr int N_NODES = 50000;
constexpr int N_EDGES = 800000;
constexpr int F_IN = 128;
constexpr int H1 = 64;
constexpr int HEADS = 4;
constexpr int D_H = 32;
constexpr int HOUT = HEADS * D_H;       // 128
constexpr int N_REL = 4;
constexpr int N_GRAPHS = 64;
constexpr int MBIG = H1 * (1 + N_REL);  // 320
constexpr int NBLK = (N_NODES + 255) / 256;  // 196

// ---- monotonic float<->uint for atomicMax on floats ----
__device__ __forceinline__ unsigned f2mono(float f) {
  unsigned u = __float_as_uint(f);
  return (u & 0x80000000u) ? ~u : (u | 0x80000000u);
}
__device__ __forceinline__ float mono2f(unsigned m) {
  unsigned u = (m & 0x80000000u) ? (m & 0x7FFFFFFFu) : ~m;
  return __uint_as_float(u);
}
constexpr unsigned MONO_NEG_INF = 0x007FFFFFu;

// ---- bf16 helpers ----
__device__ __forceinline__ unsigned short f2bf(float f) {
  unsigned u = __float_as_uint(f);
  unsigned r = (u + 0x7FFFu + ((u >> 16) & 1u)) >> 16;  // RNE
  return (unsigned short)r;
}
__device__ __forceinline__ float bflo(unsigned u) { return __uint_as_float(u << 16); }
__device__ __forceinline__ float bfhi(unsigned u) { return __uint_as_float(u & 0xFFFF0000u); }

// ---- build Wbig[128][320] = [W_root | W_rel[0..3]] ----
__global__ __launch_bounds__(256) void build_wbig(const float* __restrict__ W_root,
                                                  const float* __restrict__ W_rel,
                                                  float* __restrict__ Wbig) {
  int i = blockIdx.x * 256 + threadIdx.x;
  if (i >= F_IN * MBIG) return;
  int k = i / MBIG, c = i % MBIG;
  float v;
  if (c < H1) v = W_root[k * H1 + c];
  else {
    int r = (c - H1) >> 6, cc = (c - H1) & 63;
    v = W_rel[((size_t)r * F_IN + k) * H1 + cc];
  }
  Wbig[i] = v;
}

// ---- tiled f32 GEMM: C[N,M] = A[N,K] @ B[K,M]; K%32==0, M%64==0 ----
// optional f32 output C and/or bf16 output Cbf
__global__ __launch_bounds__(256) void gemm_f32_v2(const float* __restrict__ A,
                                                   const float* __restrict__ B,
                                                   float* __restrict__ C,
                                                   unsigned short* __restrict__ Cbf,
                                                   int N, int K, int M) {
  __shared__ float As[128][33];
  __shared__ float Bs[32][68];
  int tid = threadIdx.x;
  int tx = tid & 15, ty = tid >> 4;
  int rowBase = blockIdx.x * 128;
  int colBase = blockIdx.y * 64;
  float acc[8][4] = {};
  for (int k0 = 0; k0 < K; k0 += 32) {
#pragma unroll
    for (int it = 0; it < 4; ++it) {
      int idx = it * 256 + tid;
      int r = idx >> 3, kk4 = (idx & 7) * 4;
      int gr = rowBase + r;
      float4 v = make_float4(0.f, 0.f, 0.f, 0.f);
      if (gr < N) v = *reinterpret_cast<const float4*>(&A[(size_t)gr * K + k0 + kk4]);
      As[r][kk4 + 0] = v.x; As[r][kk4 + 1] = v.y;
      As[r][kk4 + 2] = v.z; As[r][kk4 + 3] = v.w;
    }
#pragma unroll
    for (int it = 0; it < 2; ++it) {
      int idx = it * 256 + tid;
      int kk = idx >> 4, c4 = (idx & 15) * 4;
      float4 v = *reinterpret_cast<const float4*>(&B[(size_t)(k0 + kk) * M + colBase + c4]);
      *reinterpret_cast<float4*>(&Bs[kk][c4]) = v;
    }
    __syncthreads();
#pragma unroll
    for (int kk = 0; kk < 32; ++kk) {
      float4 b4 = *reinterpret_cast<const float4*>(&Bs[kk][tx * 4]);
#pragma unroll
      for (int i = 0; i < 8; ++i) {
        float a = As[ty * 8 + i][kk];
        acc[i][0] += a * b4.x; acc[i][1] += a * b4.y;
        acc[i][2] += a * b4.z; acc[i][3] += a * b4.w;
      }
    }
    __syncthreads();
  }
#pragma unroll
  for (int i = 0; i < 8; ++i) {
    int r = rowBase + ty * 8 + i;
    if (r < N) {
      if (C) {
        float4 v = make_float4(acc[i][0], acc[i][1], acc[i][2], acc[i][3]);
        *reinterpret_cast<float4*>(&C[(size_t)r * M + colBase + tx * 4]) = v;
      }
      if (Cbf) {
        ushort4 bv;
        bv.x = f2bf(acc[i][0]); bv.y = f2bf(acc[i][1]);
        bv.z = f2bf(acc[i][2]); bv.w = f2bf(acc[i][3]);
        *reinterpret_cast<ushort4*>(&Cbf[(size_t)r * M + colBase + tx * 4]) = bv;
      }
    }
  }
}

// ---- CSR build: histogram of dst ----
__global__ __launch_bounds__(256) void k_hist(const int* __restrict__ dst,
                                              int* __restrict__ deg) {
  int e = blockIdx.x * 256 + threadIdx.x;
  if (e < N_EDGES) atomicAdd(&deg[dst[e]], 1);
}

// ---- scan stage 1: per-block sums ----
__global__ __launch_bounds__(256) void k_s1(const int* __restrict__ deg,
                                            int* __restrict__ bsum) {
  __shared__ int ss[256];
  int t = threadIdx.x;
  int i = blockIdx.x * 256 + t;
  ss[t] = (i < N_NODES) ? deg[i] : 0;
  __syncthreads();
  for (int d = 128; d > 0; d >>= 1) {
    if (t < d) ss[t] += ss[t + d];
    __syncthreads();
  }
  if (t == 0) bsum[blockIdx.x] = ss[0];
}

// ---- scan stage 2: exclusive scan of block sums ----
__global__ __launch_bounds__(256) void k_s2(const int* __restrict__ bsum,
                                            int* __restrict__ bbase,
                                            int* __restrict__ off) {
  __shared__ int ss[256];
  int t = threadIdx.x;
  int v = (t < NBLK) ? bsum[t] : 0;
  ss[t] = v;
  __syncthreads();
  for (int d = 1; d < 256; d <<= 1) {
    int u = (t >= d) ? ss[t - d] : 0;
    __syncthreads();
    ss[t] += u;
    __syncthreads();
  }
  if (t < NBLK) bbase[t] = ss[t] - v;
  if (t == NBLK - 1) off[N_NODES] = ss[t];
}

// ---- scan stage 3: block-local scan + base ----
__global__ __launch_bounds__(256) void k_s3(const int* __restrict__ deg,
                                            const int* __restrict__ bbase,
                                            int* __restrict__ off,
                                            int* __restrict__ cursor) {
  __shared__ int ss[256];
  int t = threadIdx.x;
  int i = blockIdx.x * 256 + t;
  int v = (i < N_NODES) ? deg[i] : 0;
  ss[t] = v;
  __syncthreads();
  for (int d = 1; d < 256; d <<= 1) {
    int u = (t >= d) ? ss[t - d] : 0;
    __syncthreads();
    ss[t] += u;
    __syncthreads();
  }
  if (i < N_NODES) {
    int o = bbase[blockIdx.x] + ss[t] - v;
    off[i] = o;
    cursor[i] = o;
  }
}

// ---- CSR fill: packed (src | etype<<16) ----
__global__ __launch_bounds__(256) void k_fill(const int* __restrict__ src,
                                              const int* __restrict__ dst,
                                              const int* __restrict__ etype,
                                              int* __restrict__ cursor,
                                              int* __restrict__ eprep) {
  int e = blockIdx.x * 256 + threadIdx.x;
  if (e >= N_EDGES) return;
  int pos = atomicAdd(&cursor[dst[e]], 1);
  eprep[pos] = src[e] | (etype[e] << 16);
}

// ---- RGCN: gather + mean + root + bias + relu; wave/node; 4-deep prefetch ----
__global__ __launch_bounds__(256) void rgcn_gather(const float* __restrict__ xt,
                                                   const int* __restrict__ off,
                                                   const int* __restrict__ eprep,
                                                   const float* __restrict__ b_rgcn,
                                                   float* __restrict__ h) {
  int wid = (blockIdx.x * 256 + threadIdx.x) >> 6;
  int lane = threadIdx.x & 63;
  int start = off[wid], end = off[wid + 1];
  float a0 = 0.f, a1 = 0.f, a2 = 0.f, a3 = 0.f;
  int c0 = 0, c1 = 0, c2 = 0, c3 = 0;
  int i = start;
  for (; i + 4 <= end; i += 4) {
    int p0 = eprep[i], p1 = eprep[i + 1], p2 = eprep[i + 2], p3 = eprep[i + 3];
    int s0 = p0 & 0xFFFF, r0 = p0 >> 16;
    int s1 = p1 & 0xFFFF, r1 = p1 >> 16;
    int s2 = p2 & 0xFFFF, r2 = p2 >> 16;
    int s3 = p3 & 0xFFFF, r3 = p3 >> 16;
    float v0 = xt[(size_t)s0 * MBIG + H1 + (r0 << 6) + lane];
    float v1 = xt[(size_t)s1 * MBIG + H1 + (r1 << 6) + lane];
    float v2 = xt[(size_t)s2 * MBIG + H1 + (r2 << 6) + lane];
    float v3 = xt[(size_t)s3 * MBIG + H1 + (r3 << 6) + lane];
    a0 += (r0 == 0) ? v0 : 0.f; c0 += (r0 == 0);
    a1 += (r0 == 1) ? v0 : 0.f; c1 += (r0 == 1);
    a2 += (r0 == 2) ? v0 : 0.f; c2 += (r0 == 2);
    a3 += (r0 == 3) ? v0 : 0.f; c3 += (r0 == 3);
    a0 += (r1 == 0) ? v1 : 0.f; c0 += (r1 == 0);
    a1 += (r1 == 1) ? v1 : 0.f; c1 += (r1 == 1);
    a2 += (r1 == 2) ? v1 : 0.f; c2 += (r1 == 2);
    a3 += (r1 == 3) ? v1 : 0.f; c3 += (r1 == 3);
    a0 += (r2 == 0) ? v2 : 0.f; c0 += (r2 == 0);
    a1 += (r2 == 1) ? v2 : 0.f; c1 += (r2 == 1);
    a2 += (r2 == 2) ? v2 : 0.f; c2 += (r2 == 2);
    a3 += (r2 == 3) ? v2 : 0.f; c3 += (r2 == 3);
    a0 += (r3 == 0) ? v3 : 0.f; c0 += (r3 == 0);
    a1 += (r3 == 1) ? v3 : 0.f; c1 += (r3 == 1);
    a2 += (r3 == 2) ? v3 : 0.f; c2 += (r3 == 2);
    a3 += (r3 == 3) ? v3 : 0.f; c3 += (r3 == 3);
  }
  for (; i < end; ++i) {
    int p = eprep[i];
    int s = p & 0xFFFF, r = p >> 16;
    float v = xt[(size_t)s * MBIG + H1 + (r << 6) + lane];
    a0 += (r == 0) ? v : 0.f; c0 += (r == 0);
    a1 += (r == 1) ? v : 0.f; c1 += (r == 1);
    a2 += (r == 2) ? v : 0.f; c2 += (r == 2);
    a3 += (r == 3) ? v : 0.f; c3 += (r == 3);
  }
  float v = xt[(size_t)wid * MBIG + lane] + b_rgcn[lane];
  v += a0 / (float)max(c0, 1);
  v += a1 / (float)max(c1, 1);
  v += a2 / (float)max(c2, 1);
  v += a3 / (float)max(c3, 1);
  h[(size_t)wid * H1 + lane] = fmaxf(v, 0.f);
}

// ---- attention coefficients from bf16 g, LDS-staged ----
__global__ __launch_bounds__(256) void gat_att(const unsigned short* __restrict__ gbf,
                                               const float* __restrict__ att_src,
                                               const float* __restrict__ att_dst,
                                               float* __restrict__ a_s,
                                               float* __restrict__ a_d) {
  __shared__ float gs[64][129];
  __shared__ float asrc[HOUT], adst[HOUT];
  int t = threadIdx.x;
  if (t < HOUT) { asrc[t] = att_src[t]; adst[t] = att_dst[t]; }
  int nb = blockIdx.x * 64;
#pragma unroll
  for (int it = 0; it < 8; ++it) {
    int idx = it * 256 + t;              // 2048 uint2 slots (4 ch each)
    int r = idx >> 5, c4 = (idx & 31) * 4;
    int gn = nb + r;
    uint2 v = make_uint2(0u, 0u);
    if (gn < N_NODES)
      v = *reinterpret_cast<const uint2*>(&gbf[(size_t)gn * HOUT + c4]);
    gs[r][c4 + 0] = bflo(v.x); gs[r][c4 + 1] = bfhi(v.x);
    gs[r][c4 + 2] = bflo(v.y); gs[r][c4 + 3] = bfhi(v.y);
  }
  __syncthreads();
  int n = t & 63, hh = t >> 6;
  float s = 0.f, d = 0.f;
#pragma unroll
  for (int k = 0; k < D_H; ++k) {
    float gv = gs[n][hh * D_H + k];
    s += gv * asrc[hh * D_H + k];
    d += gv * adst[hh * D_H + k];
  }
  if (nb + n < N_NODES) {
    a_s[(size_t)(nb + n) * 4 + hh] = s;
    a_d[(size_t)(nb + n) * 4 + hh] = d;
  }
}

// ---- GAT: softmax attention aggregation; wave/node; no max pass;
//      bf16 g gather; 4-deep prefetch ----
__global__ __launch_bounds__(256) void gat_gather(const unsigned short* __restrict__ gbf,
                                                  const float* __restrict__ a_s,
                                                  const float* __restrict__ a_d,
                                                  const int* __restrict__ off,
                                                  const int* __restrict__ eprep,
                                                  const float* __restrict__ b_gat,
                                                  float* __restrict__ o) {
  int wid = (blockIdx.x * 256 + threadIdx.x) >> 6;
  int lane = threadIdx.x & 63;
  int start = off[wid], end = off[wid + 1];
  int hh = lane >> 4;
  float4 ad4 = *reinterpret_cast<const float4*>(a_d + (size_t)wid * 4);
  float adh = (hh == 0) ? ad4.x : (hh == 1) ? ad4.y : (hh == 2) ? ad4.z : ad4.w;
  float ox = 0.f, oy = 0.f, den = 0.f;
  int i = start;
  for (; i + 4 <= end; i += 4) {
    int p0 = eprep[i], p1 = eprep[i + 1], p2 = eprep[i + 2], p3 = eprep[i + 3];
    int s0 = p0 & 0xFFFF, s1 = p1 & 0xFFFF, s2 = p2 & 0xFFFF, s3 = p3 & 0xFFFF;
    float as0 = a_s[(size_t)s0 * 4 + hh];
    float as1 = a_s[(size_t)s1 * 4 + hh];
    float as2 = a_s[(size_t)s2 * 4 + hh];
    float as3 = a_s[(size_t)s3 * 4 + hh];
    unsigned u0 = *reinterpret_cast<const unsigned*>(&gbf[(size_t)s0 * HOUT + lane * 2]);
    unsigned u1 = *reinterpret_cast<const unsigned*>(&gbf[(size_t)s1 * HOUT + lane * 2]);
    unsigned u2 = *reinterpret_cast<const unsigned*>(&gbf[(size_t)s2 * HOUT + lane * 2]);
    unsigned u3 = *reinterpret_cast<const unsigned*>(&gbf[(size_t)s3 * HOUT + lane * 2]);
    float e0 = as0 + adh; e0 = (e0 > 0.f) ? e0 : 0.2f * e0;
    float e1 = as1 + adh; e1 = (e1 > 0.f) ? e1 : 0.2f * e1;
    float e2 = as2 + adh; e2 = (e2 > 0.f) ? e2 : 0.2f * e2;
    float e3 = as3 + adh; e3 = (e3 > 0.f) ? e3 : 0.2f * e3;
    float x0 = __expf(e0), x1 = __expf(e1), x2 = __expf(e2), x3 = __expf(e3);
    den += x0 + x1 + x2 + x3;
    ox += x0 * bflo(u0) + x1 * bflo(u1) + x2 * bflo(u2) + x3 * bflo(u3);
    oy += x0 * bfhi(u0) + x1 * bfhi(u1) + x2 * bfhi(u2) + x3 * bfhi(u3);
  }
  for (; i < end; ++i) {
    int p = eprep[i];
    int s = p & 0xFFFF;
    float as = a_s[(size_t)s * 4 + hh];
    unsigned u = *reinterpret_cast<const unsigned*>(&gbf[(size_t)s * HOUT + lane * 2]);
    float e = as + adh; e = (e > 0.f) ? e : 0.2f * e;
    float ex = __expf(e);
    den += ex;
    ox += ex * bflo(u);
    oy += ex * bfhi(u);
  }
  float dinv = (den > 0.f) ? (1.0f / den) : 0.f;
  float2 bg = *reinterpret_cast<const float2*>(b_gat + lane * 2);
  float vx = ox * dinv + bg.x; vx = (vx > 0.f) ? vx : 0.01f * vx;
  float vy = oy * dinv + bg.y; vy = (vy > 0.f) ? vy : 0.01f * vy;
  *reinterpret_cast<float2*>(o + (size_t)wid * HOUT + lane * 2) = make_float2(vx, vy);
}

// ---- init mono buffer ----
__global__ __launch_bounds__(256) void init_mono(unsigned* __restrict__ p, int count) {
  int i = blockIdx.x * 256 + threadIdx.x;
  if (i < count) p[i] = MONO_NEG_INF;
}

// ---- head: z = leaky(o @ W1 + b1); per-graph max pool ----
__global__ __launch_bounds__(256) void final_z(const float* __restrict__ o,
                                               const float* __restrict__ W1,
                                               const float* __restrict__ b1,
                                               const int* __restrict__ batch,
                                               unsigned* __restrict__ p_mono) {
  __shared__ float os[64][129];
  __shared__ float w1s[HOUT * 16];
  __shared__ unsigned sp[N_GRAPHS * 16];
  int t = threadIdx.x;
  for (int i = t; i < N_GRAPHS * 16; i += 256) sp[i] = MONO_NEG_INF;
  for (int i = t; i < HOUT * 16; i += 256) w1s[i] = W1[i];
  int nb = blockIdx.x * 64;
#pragma unroll
  for (int it = 0; it < 8; ++it) {
    int idx = it * 256 + t;
    int r = idx >> 5, c4 = (idx & 31) * 4;
    int gn = nb + r;
    float4 v = make_float4(0.f, 0.f, 0.f, 0.f);
    if (gn < N_NODES) v = *reinterpret_cast<const float4*>(&o[(size_t)gn * HOUT + c4]);
    os[r][c4 + 0] = v.x; os[r][c4 + 1] = v.y;
    os[r][c4 + 2] = v.z; os[r][c4 + 3] = v.w;
  }
  __syncthreads();
  int n = t >> 2, jg = (t & 3) * 4;
  float z0 = b1[jg], z1 = b1[jg + 1], z2 = b1[jg + 2], z3 = b1[jg + 3];
#pragma unroll 8
  for (int k = 0; k < HOUT; ++k) {
    float v = os[n][k];
    float4 w = *reinterpret_cast<const float4*>(&w1s[k * 16 + jg]);
    z0 += v * w.x; z1 += v * w.y; z2 += v * w.z; z3 += v * w.w;
  }
  if (nb + n < N_NODES) {
    int b = batch[nb + n];
    float zz;
    zz = (z0 > 0.f) ? z0 : 0.01f * z0; atomicMax(&sp[b * 16 + jg + 0], f2mono(zz));
    zz = (z1 > 0.f) ? z1 : 0.01f * z1; atomicMax(&sp[b * 16 + jg + 1], f2mono(zz));
    zz = (z2 > 0.f) ? z2 : 0.01f * z2; atomicMax(&sp[b * 16 + jg + 2], f2mono(zz));
    zz = (z3 > 0.f) ? z3 : 0.01f * z3; atomicMax(&sp[b * 16 + jg + 3], f2mono(zz));
  }
  __syncthreads();
  for (int i = t; i < N_GRAPHS * 16; i += 256) {
    unsigned v = sp[i];
    if (v != MONO_NEG_INF) atomicMax(p_mono + i, v);
  }
}

// ---- y = p @ W2 + b2 ----
__global__ void final_y(const unsigned* __restrict__ p_mono,
                        const float* __restrict__ W2,
                        const float* __restrict__ b2,
                        float* __restrict__ y) {
  int gr = threadIdx.x;
  if (gr >= N_GRAPHS) return;
  float acc = b2[0];
#pragma unroll
  for (int k = 0; k < 16; ++k) acc += mono2f(p_mono[gr * 16 + k]) * W2[k];
  y[gr] = acc;
}

extern "C" void kernel_launch(void* const* d_in, const int* in_sizes, int n_in,
                              void* d_out, int out_size, void* d_ws, size_t ws_size,
                              hipStream_t stream) {
  const float* x       = (const float*)d_in[0];
  const int*   eidx    = (const int*)d_in[1];
  const int*   etype   = (const int*)d_in[2];
  const int*   batch   = (const int*)d_in[3];
  const float* W_rel   = (const float*)d_in[4];
  const float* W_root  = (const float*)d_in[5];
  const float* b_rgcn  = (const float*)d_in[6];
  const float* W_gat   = (const float*)d_in[7];
  const float* att_src = (const float*)d_in[8];
  const float* att_dst = (const float*)d_in[9];
  const float* b_gat   = (const float*)d_in[10];
  const float* W1      = (const float*)d_in[11];
  const float* b1      = (const float*)d_in[12];
  const float* W2      = (const float*)d_in[13];
  const float* b2      = (const float*)d_in[14];
  float* y = (float*)d_out;

  const int* src = eidx;
  const int* dst = eidx + N_EDGES;

  float* ws = (float*)d_ws;
  const size_t OFF_XT  = 0;           // 16,000,000  xt [N,320]
  const size_t OFF_GBF = 0;           //  1,600,000  g bf16 (reuses xt after rgcn)
  const size_t OFF_O   = 6400000;     //  6,400,000  o [N,128] f32
  const size_t OFF_H   = 16000000;    //  3,200,000  h [N,64]
  const size_t OFF_AS  = 19200000;    //    200,000  a_src
  const size_t OFF_AD  = 19400000;    //    200,000  a_dst
  const size_t OFF_WB  = 19600000;    //     40,960  Wbig
  const size_t OFF_PM  = 19640960;    //      1,024  pool max (mono u32)
  const size_t OFF_DEG = 19642000;    //     50,000  deg (int)
  const size_t OFF_OFFS= 19692000;    //     50,001  off (int)
  const size_t OFF_CUR = 19742016;    //     50,000  cursor (int)
  const size_t OFF_EP  = 19792016;    //    800,000  eprep (int)
  const size_t OFF_BS  = 20592016;    //        196
  const size_t OFF_BB  = 20592212;    //        196
  const size_t TOTAL_F = 20592512;
  if (ws_size < TOTAL_F * sizeof(float)) return;

  float* xt    = ws + OFF_XT;
  unsigned short* gbf = (unsigned short*)(ws + OFF_GBF);
  float* o     = ws + OFF_O;
  float* h     = ws + OFF_H;
  float* a_s   = ws + OFF_AS;
  float* a_d   = ws + OFF_AD;
  float* wbig  = ws + OFF_WB;
  unsigned* pm = (unsigned*)(ws + OFF_PM);
  int* deg     = (int*)(ws + OFF_DEG);
  int* offs    = (int*)(ws + OFF_OFFS);
  int* cursor  = (int*)(ws + OFF_CUR);
  int* eprep   = (int*)(ws + OFF_EP);
  int* bsum    = (int*)(ws + OFF_BS);
  int* bbase   = (int*)(ws + OFF_BB);

  // CSR build
  hipMemsetAsync(deg, 0, N_NODES * sizeof(int), stream);
  k_hist<<<(N_EDGES + 255) / 256, 256, 0, stream>>>(dst, deg);
  k_s1<<<NBLK, 256, 0, stream>>>(deg, bsum);
  k_s2<<<1, 256, 0, stream>>>(bsum, bbase, offs);
  k_s3<<<NBLK, 256, 0, stream>>>(deg, bbase, offs, cursor);
  k_fill<<<(N_EDGES + 255) / 256, 256, 0, stream>>>(src, dst, etype, cursor, eprep);

  // xt = x @ [W_root | W_rel]
  build_wbig<<<(F_IN * MBIG + 255) / 256, 256, 0, stream>>>(W_root, W_rel, wbig);
  {
    dim3 grid((N_NODES + 127) / 128, MBIG / 64);
    gemm_f32_v2<<<grid, 256, 0, stream>>>(x, wbig, xt, nullptr, N_NODES, F_IN, MBIG);
  }

  // RGCN gather -> h
  rgcn_gather<<<N_NODES / 4, 256, 0, stream>>>(xt, offs, eprep, b_rgcn, h);

  // g(bf16) = h @ W_gat  (xt region dead; only bf16 copy emitted)
  {
    dim3 grid((N_NODES + 127) / 128, HOUT / 64);
    gemm_f32_v2<<<grid, 256, 0, stream>>>(h, W_gat, nullptr, gbf, N_NODES, H1, HOUT);
  }

  // attention coefficients (bf16 g)
  gat_att<<<(N_NODES + 63) / 64, 256, 0, stream>>>(gbf, att_src, att_dst, a_s, a_d);

  // GAT gather -> o (normalized + bias + leaky), no max pass
  gat_gather<<<N_NODES / 4, 256, 0, stream>>>(gbf, a_s, a_d, offs, eprep, b_gat, o);

  // head + per-graph max pool
  init_mono<<<(N_GRAPHS * 16 + 255) / 256, 256, 0, stream>>>(pm, N_GRAPHS * 16);
  final_z<<<(N_NODES + 63) / 64, 256, 0, stream>>>(o, W1, b1, batch, pm);
  final_y<<<1, 64, 0, stream>>>(pm, W2, b2, y);
}

// Round 5
// 281.403 us; speedup vs baseline: 8.7065x; 1.0778x over previous
//
#include <hip/hip_runtime.h>
#include <hip/hip_bf16.h>

constexpr int N_NODES = 50000;
constexpr int N_EDGES = 800000;
constexpr int F_IN = 128;
constexpr int H1 = 64;
constexpr int HEADS = 4;
constexpr int D_H = 32;
constexpr int HOUT = HEADS * D_H;       // 128
constexpr int N_REL = 4;
constexpr int N_GRAPHS = 64;
constexpr int MBIG = H1 * (1 + N_REL);  // 320
constexpr int NBLK = (N_NODES + 255) / 256;  // 196

typedef __attribute__((ext_vector_type(8))) short bf16x8;
typedef __attribute__((ext_vector_type(4))) float f32x4;

// ---- monotonic float<->uint for atomicMax on floats ----
__device__ __forceinline__ unsigned f2mono(float f) {
  unsigned u = __float_as_uint(f);
  return (u & 0x80000000u) ? ~u : (u | 0x80000000u);
}
__device__ __forceinline__ float mono2f(unsigned m) {
  unsigned u = (m & 0x80000000u) ? (m & 0x7FFFFFFFu) : ~m;
  return __uint_as_float(u);
}
constexpr unsigned MONO_NEG_INF = 0x007FFFFFu;

// ---- bf16 helpers ----
__device__ __forceinline__ unsigned short f2bf(float f) {
  unsigned u = __float_as_uint(f);
  unsigned r = (u + 0x7FFFu + ((u >> 16) & 1u)) >> 16;  // RNE
  return (unsigned short)r;
}
__device__ __forceinline__ float bf2f(unsigned short h) {
  return __uint_as_float((unsigned)h << 16);
}
__device__ __forceinline__ float bflo(unsigned u) { return __uint_as_float(u << 16); }
__device__ __forceinline__ float bfhi(unsigned u) { return __uint_as_float(u & 0xFFFF0000u); }

// ---- build transposed bf16 hi/lo weights:
//      WbigT[320][128] = [W_root | W_rel]^T, WgatT[128][64] = W_gat^T ----
__global__ __launch_bounds__(256) void build_wT(const float* __restrict__ W_root,
                                                const float* __restrict__ W_rel,
                                                const float* __restrict__ W_gat,
                                                unsigned short* __restrict__ WbT_hi,
                                                unsigned short* __restrict__ WbT_lo,
                                                unsigned short* __restrict__ WgT_hi,
                                                unsigned short* __restrict__ WgT_lo) {
  int i = blockIdx.x * 256 + threadIdx.x;
  if (i < MBIG * F_IN) {               // WbigT[c][k]
    int c = i / F_IN, k = i % F_IN;
    float w = (c < H1) ? W_root[k * H1 + c]
                       : W_rel[((size_t)(((c - H1) >> 6) * F_IN + k)) * H1 + ((c - H1) & 63)];
    unsigned short hi = f2bf(w);
    WbT_hi[i] = hi;
    WbT_lo[i] = f2bf(w - bf2f(hi));
  } else {
    int j = i - MBIG * F_IN;
    if (j < HOUT * H1) {               // WgatT[c][k]
      int c = j / H1, k = j % H1;
      float w = W_gat[k * HOUT + c];
      unsigned short hi = f2bf(w);
      WgT_hi[j] = hi;
      WgT_lo[j] = f2bf(w - bf2f(hi));
    }
  }
}

// ---- split-bf16 MFMA GEMM: C[N,M] = A[N,K] @ B[K,M] (~f32 precision).
//      A f32; B given transposed bf16 hi/lo BT[M][K]. K in {64,128}, M%64==0.
//      Block: 256 thr / 4 waves, 64-row tile; A staged in LDS once;
//      col-loop over M/64 tiles; B frags straight from global (L2-hot). ----
__global__ __launch_bounds__(256) void gemm_mfma(const float* __restrict__ A,
                                                 const unsigned short* __restrict__ BT_hi,
                                                 const unsigned short* __restrict__ BT_lo,
                                                 float* __restrict__ C,
                                                 unsigned short* __restrict__ Cbf,
                                                 int N, int K, int M) {
  __shared__ unsigned short Ahi[64 * 136];   // stride Kp=K+8 (136 or 72)
  __shared__ unsigned short Alo[64 * 136];
  const int Kp = K + 8;
  const int tid = threadIdx.x;
  const int rowBase = blockIdx.x * 64;
  // ---- stage A tile f32 -> bf16 hi/lo ----
  const int kq = K >> 2;                     // float4 per row
  const int kql = (K == 128) ? 5 : 4;
  const int slots = 64 * kq;
  for (int s = tid; s < slots; s += 256) {
    int r = s >> kql, c4 = (s & (kq - 1)) << 2;
    int gr = rowBase + r;
    float4 v = make_float4(0.f, 0.f, 0.f, 0.f);
    if (gr < N) v = *reinterpret_cast<const float4*>(&A[(size_t)gr * K + c4]);
    ushort4 hi, lo;
    hi.x = f2bf(v.x); lo.x = f2bf(v.x - bf2f(hi.x));
    hi.y = f2bf(v.y); lo.y = f2bf(v.y - bf2f(hi.y));
    hi.z = f2bf(v.z); lo.z = f2bf(v.z - bf2f(hi.z));
    hi.w = f2bf(v.w); lo.w = f2bf(v.w - bf2f(hi.w));
    *reinterpret_cast<ushort4*>(&Ahi[r * Kp + c4]) = hi;
    *reinterpret_cast<ushort4*>(&Alo[r * Kp + c4]) = lo;
  }
  __syncthreads();
  const int wv = tid >> 6, lane = tid & 63;
  const int wr = (wv >> 1) * 32, wc = (wv & 1) * 32;
  const int lrow = lane & 15, lkc = lane >> 4;
  for (int ct = 0; ct < (M >> 6); ++ct) {
    const int colBase = ct * 64;
    f32x4 acc[2][2] = {};
    for (int ks = 0; ks < K; ks += 32) {
      bf16x8 ah[2], al[2], bh[2], bl[2];
#pragma unroll
      for (int fr = 0; fr < 2; ++fr) {
        int r = wr + fr * 16 + lrow;
        ah[fr] = *reinterpret_cast<const bf16x8*>(&Ahi[r * Kp + ks + lkc * 8]);
        al[fr] = *reinterpret_cast<const bf16x8*>(&Alo[r * Kp + ks + lkc * 8]);
      }
#pragma unroll
      for (int fc = 0; fc < 2; ++fc) {
        int c = colBase + wc + fc * 16 + lrow;
        bh[fc] = *reinterpret_cast<const bf16x8*>(&BT_hi[(size_t)c * K + ks + lkc * 8]);
        bl[fc] = *reinterpret_cast<const bf16x8*>(&BT_lo[(size_t)c * K + ks + lkc * 8]);
      }
#pragma unroll
      for (int fr = 0; fr < 2; ++fr)
#pragma unroll
        for (int fc = 0; fc < 2; ++fc) {
          acc[fr][fc] = __builtin_amdgcn_mfma_f32_16x16x32_bf16(ah[fr], bh[fc], acc[fr][fc], 0, 0, 0);
          acc[fr][fc] = __builtin_amdgcn_mfma_f32_16x16x32_bf16(ah[fr], bl[fc], acc[fr][fc], 0, 0, 0);
          acc[fr][fc] = __builtin_amdgcn_mfma_f32_16x16x32_bf16(al[fr], bh[fc], acc[fr][fc], 0, 0, 0);
        }
    }
#pragma unroll
    for (int fr = 0; fr < 2; ++fr) {
#pragma unroll
      for (int i = 0; i < 4; ++i) {
        int row = rowBase + wr + fr * 16 + lkc * 4 + i;
        if (row < N) {
#pragma unroll
          for (int fc = 0; fc < 2; ++fc) {
            int col = colBase + wc + fc * 16 + lrow;
            float v = acc[fr][fc][i];
            if (C) C[(size_t)row * M + col] = v;
            if (Cbf) Cbf[(size_t)row * M + col] = f2bf(v);
          }
        }
      }
    }
  }
}

// ---- CSR build: histogram of dst ----
__global__ __launch_bounds__(256) void k_hist(const int* __restrict__ dst,
                                              int* __restrict__ deg) {
  int e = blockIdx.x * 256 + threadIdx.x;
  if (e < N_EDGES) atomicAdd(&deg[dst[e]], 1);
}

// ---- scan stage 1: per-block sums ----
__global__ __launch_bounds__(256) void k_s1(const int* __restrict__ deg,
                                            int* __restrict__ bsum) {
  __shared__ int ss[256];
  int t = threadIdx.x;
  int i = blockIdx.x * 256 + t;
  ss[t] = (i < N_NODES) ? deg[i] : 0;
  __syncthreads();
  for (int d = 128; d > 0; d >>= 1) {
    if (t < d) ss[t] += ss[t + d];
    __syncthreads();
  }
  if (t == 0) bsum[blockIdx.x] = ss[0];
}

// ---- scan stage 2: exclusive scan of block sums ----
__global__ __launch_bounds__(256) void k_s2(const int* __restrict__ bsum,
                                            int* __restrict__ bbase,
                                            int* __restrict__ off) {
  __shared__ int ss[256];
  int t = threadIdx.x;
  int v = (t < NBLK) ? bsum[t] : 0;
  ss[t] = v;
  __syncthreads();
  for (int d = 1; d < 256; d <<= 1) {
    int u = (t >= d) ? ss[t - d] : 0;
    __syncthreads();
    ss[t] += u;
    __syncthreads();
  }
  if (t < NBLK) bbase[t] = ss[t] - v;
  if (t == NBLK - 1) off[N_NODES] = ss[t];
}

// ---- scan stage 3: block-local scan + base ----
__global__ __launch_bounds__(256) void k_s3(const int* __restrict__ deg,
                                            const int* __restrict__ bbase,
                                            int* __restrict__ off,
                                            int* __restrict__ cursor) {
  __shared__ int ss[256];
  int t = threadIdx.x;
  int i = blockIdx.x * 256 + t;
  int v = (i < N_NODES) ? deg[i] : 0;
  ss[t] = v;
  __syncthreads();
  for (int d = 1; d < 256; d <<= 1) {
    int u = (t >= d) ? ss[t - d] : 0;
    __syncthreads();
    ss[t] += u;
    __syncthreads();
  }
  if (i < N_NODES) {
    int o = bbase[blockIdx.x] + ss[t] - v;
    off[i] = o;
    cursor[i] = o;
  }
}

// ---- CSR fill: packed (src | etype<<16) ----
__global__ __launch_bounds__(256) void k_fill(const int* __restrict__ src,
                                              const int* __restrict__ dst,
                                              const int* __restrict__ etype,
                                              int* __restrict__ cursor,
                                              int* __restrict__ eprep) {
  int e = blockIdx.x * 256 + threadIdx.x;
  if (e >= N_EDGES) return;
  int pos = atomicAdd(&cursor[dst[e]], 1);
  eprep[pos] = src[e] | (etype[e] << 16);
}

// ---- RGCN: gather + mean + root + bias + relu; wave/node; 4-deep prefetch ----
__global__ __launch_bounds__(256) void rgcn_gather(const float* __restrict__ xt,
                                                   const int* __restrict__ off,
                                                   const int* __restrict__ eprep,
                                                   const float* __restrict__ b_rgcn,
                                                   float* __restrict__ h) {
  int wid = (blockIdx.x * 256 + threadIdx.x) >> 6;
  int lane = threadIdx.x & 63;
  int start = off[wid], end = off[wid + 1];
  float a0 = 0.f, a1 = 0.f, a2 = 0.f, a3 = 0.f;
  int c0 = 0, c1 = 0, c2 = 0, c3 = 0;
  int i = start;
  for (; i + 4 <= end; i += 4) {
    int p0 = eprep[i], p1 = eprep[i + 1], p2 = eprep[i + 2], p3 = eprep[i + 3];
    int s0 = p0 & 0xFFFF, r0 = p0 >> 16;
    int s1 = p1 & 0xFFFF, r1 = p1 >> 16;
    int s2 = p2 & 0xFFFF, r2 = p2 >> 16;
    int s3 = p3 & 0xFFFF, r3 = p3 >> 16;
    float v0 = xt[(size_t)s0 * MBIG + H1 + (r0 << 6) + lane];
    float v1 = xt[(size_t)s1 * MBIG + H1 + (r1 << 6) + lane];
    float v2 = xt[(size_t)s2 * MBIG + H1 + (r2 << 6) + lane];
    float v3 = xt[(size_t)s3 * MBIG + H1 + (r3 << 6) + lane];
    a0 += (r0 == 0) ? v0 : 0.f; c0 += (r0 == 0);
    a1 += (r0 == 1) ? v0 : 0.f; c1 += (r0 == 1);
    a2 += (r0 == 2) ? v0 : 0.f; c2 += (r0 == 2);
    a3 += (r0 == 3) ? v0 : 0.f; c3 += (r0 == 3);
    a0 += (r1 == 0) ? v1 : 0.f; c0 += (r1 == 0);
    a1 += (r1 == 1) ? v1 : 0.f; c1 += (r1 == 1);
    a2 += (r1 == 2) ? v1 : 0.f; c2 += (r1 == 2);
    a3 += (r1 == 3) ? v1 : 0.f; c3 += (r1 == 3);
    a0 += (r2 == 0) ? v2 : 0.f; c0 += (r2 == 0);
    a1 += (r2 == 1) ? v2 : 0.f; c1 += (r2 == 1);
    a2 += (r2 == 2) ? v2 : 0.f; c2 += (r2 == 2);
    a3 += (r2 == 3) ? v2 : 0.f; c3 += (r2 == 3);
    a0 += (r3 == 0) ? v3 : 0.f; c0 += (r3 == 0);
    a1 += (r3 == 1) ? v3 : 0.f; c1 += (r3 == 1);
    a2 += (r3 == 2) ? v3 : 0.f; c2 += (r3 == 2);
    a3 += (r3 == 3) ? v3 : 0.f; c3 += (r3 == 3);
  }
  for (; i < end; ++i) {
    int p = eprep[i];
    int s = p & 0xFFFF, r = p >> 16;
    float v = xt[(size_t)s * MBIG + H1 + (r << 6) + lane];
    a0 += (r == 0) ? v : 0.f; c0 += (r == 0);
    a1 += (r == 1) ? v : 0.f; c1 += (r == 1);
    a2 += (r == 2) ? v : 0.f; c2 += (r == 2);
    a3 += (r == 3) ? v : 0.f; c3 += (r == 3);
  }
  float v = xt[(size_t)wid * MBIG + lane] + b_rgcn[lane];
  v += a0 / (float)max(c0, 1);
  v += a1 / (float)max(c1, 1);
  v += a2 / (float)max(c2, 1);
  v += a3 / (float)max(c3, 1);
  h[(size_t)wid * H1 + lane] = fmaxf(v, 0.f);
}

// ---- attention coefficients from bf16 g, LDS-staged ----
__global__ __launch_bounds__(256) void gat_att(const unsigned short* __restrict__ gbf,
                                               const float* __restrict__ att_src,
                                               const float* __restrict__ att_dst,
                                               float* __restrict__ a_s,
                                               float* __restrict__ a_d) {
  __shared__ float gs[64][129];
  __shared__ float asrc[HOUT], adst[HOUT];
  int t = threadIdx.x;
  if (t < HOUT) { asrc[t] = att_src[t]; adst[t] = att_dst[t]; }
  int nb = blockIdx.x * 64;
#pragma unroll
  for (int it = 0; it < 8; ++it) {
    int idx = it * 256 + t;
    int r = idx >> 5, c4 = (idx & 31) * 4;
    int gn = nb + r;
    uint2 v = make_uint2(0u, 0u);
    if (gn < N_NODES)
      v = *reinterpret_cast<const uint2*>(&gbf[(size_t)gn * HOUT + c4]);
    gs[r][c4 + 0] = bflo(v.x); gs[r][c4 + 1] = bfhi(v.x);
    gs[r][c4 + 2] = bflo(v.y); gs[r][c4 + 3] = bfhi(v.y);
  }
  __syncthreads();
  int n = t & 63, hh = t >> 6;
  float s = 0.f, d = 0.f;
#pragma unroll
  for (int k = 0; k < D_H; ++k) {
    float gv = gs[n][hh * D_H + k];
    s += gv * asrc[hh * D_H + k];
    d += gv * adst[hh * D_H + k];
  }
  if (nb + n < N_NODES) {
    a_s[(size_t)(nb + n) * 4 + hh] = s;
    a_d[(size_t)(nb + n) * 4 + hh] = d;
  }
}

// ---- GAT: softmax attention aggregation; wave/node; no max pass;
//      bf16 g gather; 4-deep prefetch ----
__global__ __launch_bounds__(256) void gat_gather(const unsigned short* __restrict__ gbf,
                                                  const float* __restrict__ a_s,
                                                  const float* __restrict__ a_d,
                                                  const int* __restrict__ off,
                                                  const int* __restrict__ eprep,
                                                  const float* __restrict__ b_gat,
                                                  float* __restrict__ o) {
  int wid = (blockIdx.x * 256 + threadIdx.x) >> 6;
  int lane = threadIdx.x & 63;
  int start = off[wid], end = off[wid + 1];
  int hh = lane >> 4;
  float4 ad4 = *reinterpret_cast<const float4*>(a_d + (size_t)wid * 4);
  float adh = (hh == 0) ? ad4.x : (hh == 1) ? ad4.y : (hh == 2) ? ad4.z : ad4.w;
  float ox = 0.f, oy = 0.f, den = 0.f;
  int i = start;
  for (; i + 4 <= end; i += 4) {
    int p0 = eprep[i], p1 = eprep[i + 1], p2 = eprep[i + 2], p3 = eprep[i + 3];
    int s0 = p0 & 0xFFFF, s1 = p1 & 0xFFFF, s2 = p2 & 0xFFFF, s3 = p3 & 0xFFFF;
    float as0 = a_s[(size_t)s0 * 4 + hh];
    float as1 = a_s[(size_t)s1 * 4 + hh];
    float as2 = a_s[(size_t)s2 * 4 + hh];
    float as3 = a_s[(size_t)s3 * 4 + hh];
    unsigned u0 = *reinterpret_cast<const unsigned*>(&gbf[(size_t)s0 * HOUT + lane * 2]);
    unsigned u1 = *reinterpret_cast<const unsigned*>(&gbf[(size_t)s1 * HOUT + lane * 2]);
    unsigned u2 = *reinterpret_cast<const unsigned*>(&gbf[(size_t)s2 * HOUT + lane * 2]);
    unsigned u3 = *reinterpret_cast<const unsigned*>(&gbf[(size_t)s3 * HOUT + lane * 2]);
    float e0 = as0 + adh; e0 = (e0 > 0.f) ? e0 : 0.2f * e0;
    float e1 = as1 + adh; e1 = (e1 > 0.f) ? e1 : 0.2f * e1;
    float e2 = as2 + adh; e2 = (e2 > 0.f) ? e2 : 0.2f * e2;
    float e3 = as3 + adh; e3 = (e3 > 0.f) ? e3 : 0.2f * e3;
    float x0 = __expf(e0), x1 = __expf(e1), x2 = __expf(e2), x3 = __expf(e3);
    den += x0 + x1 + x2 + x3;
    ox += x0 * bflo(u0) + x1 * bflo(u1) + x2 * bflo(u2) + x3 * bflo(u3);
    oy += x0 * bfhi(u0) + x1 * bfhi(u1) + x2 * bfhi(u2) + x3 * bfhi(u3);
  }
  for (; i < end; ++i) {
    int p = eprep[i];
    int s = p & 0xFFFF;
    float as = a_s[(size_t)s * 4 + hh];
    unsigned u = *reinterpret_cast<const unsigned*>(&gbf[(size_t)s * HOUT + lane * 2]);
    float e = as + adh; e = (e > 0.f) ? e : 0.2f * e;
    float ex = __expf(e);
    den += ex;
    ox += ex * bflo(u);
    oy += ex * bfhi(u);
  }
  float dinv = (den > 0.f) ? (1.0f / den) : 0.f;
  float2 bg = *reinterpret_cast<const float2*>(b_gat + lane * 2);
  float vx = ox * dinv + bg.x; vx = (vx > 0.f) ? vx : 0.01f * vx;
  float vy = oy * dinv + bg.y; vy = (vy > 0.f) ? vy : 0.01f * vy;
  *reinterpret_cast<float2*>(o + (size_t)wid * HOUT + lane * 2) = make_float2(vx, vy);
}

// ---- init mono buffer ----
__global__ __launch_bounds__(256) void init_mono(unsigned* __restrict__ p, int count) {
  int i = blockIdx.x * 256 + threadIdx.x;
  if (i < count) p[i] = MONO_NEG_INF;
}

// ---- head: z = leaky(o @ W1 + b1); per-graph max pool ----
__global__ __launch_bounds__(256) void final_z(const float* __restrict__ o,
                                               const float* __restrict__ W1,
                                               const float* __restrict__ b1,
                                               const int* __restrict__ batch,
                                               unsigned* __restrict__ p_mono) {
  __shared__ float os[64][129];
  __shared__ float w1s[HOUT * 16];
  __shared__ unsigned sp[N_GRAPHS * 16];
  int t = threadIdx.x;
  for (int i = t; i < N_GRAPHS * 16; i += 256) sp[i] = MONO_NEG_INF;
  for (int i = t; i < HOUT * 16; i += 256) w1s[i] = W1[i];
  int nb = blockIdx.x * 64;
#pragma unroll
  for (int it = 0; it < 8; ++it) {
    int idx = it * 256 + t;
    int r = idx >> 5, c4 = (idx & 31) * 4;
    int gn = nb + r;
    float4 v = make_float4(0.f, 0.f, 0.f, 0.f);
    if (gn < N_NODES) v = *reinterpret_cast<const float4*>(&o[(size_t)gn * HOUT + c4]);
    os[r][c4 + 0] = v.x; os[r][c4 + 1] = v.y;
    os[r][c4 + 2] = v.z; os[r][c4 + 3] = v.w;
  }
  __syncthreads();
  int n = t >> 2, jg = (t & 3) * 4;
  float z0 = b1[jg], z1 = b1[jg + 1], z2 = b1[jg + 2], z3 = b1[jg + 3];
#pragma unroll 8
  for (int k = 0; k < HOUT; ++k) {
    float v = os[n][k];
    float4 w = *reinterpret_cast<const float4*>(&w1s[k * 16 + jg]);
    z0 += v * w.x; z1 += v * w.y; z2 += v * w.z; z3 += v * w.w;
  }
  if (nb + n < N_NODES) {
    int b = batch[nb + n];
    float zz;
    zz = (z0 > 0.f) ? z0 : 0.01f * z0; atomicMax(&sp[b * 16 + jg + 0], f2mono(zz));
    zz = (z1 > 0.f) ? z1 : 0.01f * z1; atomicMax(&sp[b * 16 + jg + 1], f2mono(zz));
    zz = (z2 > 0.f) ? z2 : 0.01f * z2; atomicMax(&sp[b * 16 + jg + 2], f2mono(zz));
    zz = (z3 > 0.f) ? z3 : 0.01f * z3; atomicMax(&sp[b * 16 + jg + 3], f2mono(zz));
  }
  __syncthreads();
  for (int i = t; i < N_GRAPHS * 16; i += 256) {
    unsigned v = sp[i];
    if (v != MONO_NEG_INF) atomicMax(p_mono + i, v);
  }
}

// ---- y = p @ W2 + b2 ----
__global__ void final_y(const unsigned* __restrict__ p_mono,
                        const float* __restrict__ W2,
                        const float* __restrict__ b2,
                        float* __restrict__ y) {
  int gr = threadIdx.x;
  if (gr >= N_GRAPHS) return;
  float acc = b2[0];
#pragma unroll
  for (int k = 0; k < 16; ++k) acc += mono2f(p_mono[gr * 16 + k]) * W2[k];
  y[gr] = acc;
}

extern "C" void kernel_launch(void* const* d_in, const int* in_sizes, int n_in,
                              void* d_out, int out_size, void* d_ws, size_t ws_size,
                              hipStream_t stream) {
  const float* x       = (const float*)d_in[0];
  const int*   eidx    = (const int*)d_in[1];
  const int*   etype   = (const int*)d_in[2];
  const int*   batch   = (const int*)d_in[3];
  const float* W_rel   = (const float*)d_in[4];
  const float* W_root  = (const float*)d_in[5];
  const float* b_rgcn  = (const float*)d_in[6];
  const float* W_gat   = (const float*)d_in[7];
  const float* att_src = (const float*)d_in[8];
  const float* att_dst = (const float*)d_in[9];
  const float* b_gat   = (const float*)d_in[10];
  const float* W1      = (const float*)d_in[11];
  const float* b1      = (const float*)d_in[12];
  const float* W2      = (const float*)d_in[13];
  const float* b2      = (const float*)d_in[14];
  float* y = (float*)d_out;

  const int* src = eidx;
  const int* dst = eidx + N_EDGES;

  float* ws = (float*)d_ws;
  const size_t OFF_XT  = 0;           // 16,000,000  xt [N,320] f32
  const size_t OFF_GBF = 0;           //  1,600,000  g bf16 (reuses xt after rgcn)
  const size_t OFF_O   = 6400000;     //  6,400,000  o [N,128] f32
  const size_t OFF_H   = 16000000;    //  3,200,000  h [N,64]
  const size_t OFF_AS  = 19200000;    //    200,000  a_src
  const size_t OFF_AD  = 19400000;    //    200,000  a_dst
  const size_t OFF_PM  = 19600000;    //      1,024  pool max (mono u32)
  const size_t OFF_DEG = 19602000;    //     50,000  deg (int)
  const size_t OFF_OFFS= 19652000;    //     50,001  off (int)
  const size_t OFF_CUR = 19702016;    //     50,000  cursor (int)
  const size_t OFF_EP  = 19752016;    //    800,000  eprep (int)
  const size_t OFF_BS  = 20552016;    //        196
  const size_t OFF_BB  = 20552212;    //        196
  const size_t OFF_WBH = 20552512;    //     20,480  WbigT_hi (40960 u16)
  const size_t OFF_WBL = 20572992;    //     20,480  WbigT_lo
  const size_t OFF_WGH = 20593472;    //      4,096  WgatT_hi (8192 u16)
  const size_t OFF_WGL = 20597568;    //      4,096  WgatT_lo
  const size_t TOTAL_F = 20601664;
  if (ws_size < TOTAL_F * sizeof(float)) return;

  float* xt    = ws + OFF_XT;
  unsigned short* gbf = (unsigned short*)(ws + OFF_GBF);
  float* o     = ws + OFF_O;
  float* h     = ws + OFF_H;
  float* a_s   = ws + OFF_AS;
  float* a_d   = ws + OFF_AD;
  unsigned* pm = (unsigned*)(ws + OFF_PM);
  int* deg     = (int*)(ws + OFF_DEG);
  int* offs    = (int*)(ws + OFF_OFFS);
  int* cursor  = (int*)(ws + OFF_CUR);
  int* eprep   = (int*)(ws + OFF_EP);
  int* bsum    = (int*)(ws + OFF_BS);
  int* bbase   = (int*)(ws + OFF_BB);
  unsigned short* wbt_hi = (unsigned short*)(ws + OFF_WBH);
  unsigned short* wbt_lo = (unsigned short*)(ws + OFF_WBL);
  unsigned short* wgt_hi = (unsigned short*)(ws + OFF_WGH);
  unsigned short* wgt_lo = (unsigned short*)(ws + OFF_WGL);

  // CSR build
  hipMemsetAsync(deg, 0, N_NODES * sizeof(int), stream);
  k_hist<<<(N_EDGES + 255) / 256, 256, 0, stream>>>(dst, deg);
  k_s1<<<NBLK, 256, 0, stream>>>(deg, bsum);
  k_s2<<<1, 256, 0, stream>>>(bsum, bbase, offs);
  k_s3<<<NBLK, 256, 0, stream>>>(deg, bbase, offs, cursor);
  k_fill<<<(N_EDGES + 255) / 256, 256, 0, stream>>>(src, dst, etype, cursor, eprep);

  // transposed bf16 hi/lo weights
  build_wT<<<(MBIG * F_IN + HOUT * H1 + 255) / 256, 256, 0, stream>>>(
      W_root, W_rel, W_gat, wbt_hi, wbt_lo, wgt_hi, wgt_lo);

  // xt = x @ [W_root | W_rel]  (split-bf16 MFMA, ~f32 precision)
  gemm_mfma<<<(N_NODES + 63) / 64, 256, 0, stream>>>(
      x, wbt_hi, wbt_lo, xt, nullptr, N_NODES, F_IN, MBIG);

  // RGCN gather -> h
  rgcn_gather<<<N_NODES / 4, 256, 0, stream>>>(xt, offs, eprep, b_rgcn, h);

  // g(bf16) = h @ W_gat  (xt region dead; only bf16 output)
  gemm_mfma<<<(N_NODES + 63) / 64, 256, 0, stream>>>(
      h, wgt_hi, wgt_lo, nullptr, gbf, N_NODES, H1, HOUT);

  // attention coefficients (bf16 g)
  gat_att<<<(N_NODES + 63) / 64, 256, 0, stream>>>(gbf, att_src, att_dst, a_s, a_d);

  // GAT gather -> o (normalized + bias + leaky), no max pass
  gat_gather<<<N_NODES / 4, 256, 0, stream>>>(gbf, a_s, a_d, offs, eprep, b_gat, o);

  // head + per-graph max pool
  init_mono<<<(N_GRAPHS * 16 + 255) / 256, 256, 0, stream>>>(pm, N_GRAPHS * 16);
  final_z<<<(N_NODES + 63) / 64, 256, 0, stream>>>(o, W1, b1, batch, pm);
  final_y<<<1, 64, 0, stream>>>(pm, W2, b2, y);
}

// Round 6
// 276.382 us; speedup vs baseline: 8.8646x; 1.0182x over previous
//
#include <hip/hip_runtime.h>
#include <hip/hip_bf16.h>

constexpr int N_NODES = 50000;
constexpr int N_EDGES = 800000;
constexpr int F_IN = 128;
constexpr int H1 = 64;
constexpr int HEADS = 4;
constexpr int D_H = 32;
constexpr int HOUT = HEADS * D_H;       // 128
constexpr int N_REL = 4;
constexpr int N_GRAPHS = 64;
constexpr int MBIG = H1 * (1 + N_REL);  // 320
constexpr int NBLK = (N_NODES + 255) / 256;  // 196

typedef __attribute__((ext_vector_type(8))) short bf16x8;
typedef __attribute__((ext_vector_type(4))) float f32x4;

// ---- monotonic float<->uint for atomicMax on floats ----
__device__ __forceinline__ unsigned f2mono(float f) {
  unsigned u = __float_as_uint(f);
  return (u & 0x80000000u) ? ~u : (u | 0x80000000u);
}
__device__ __forceinline__ float mono2f(unsigned m) {
  unsigned u = (m & 0x80000000u) ? (m & 0x7FFFFFFFu) : ~m;
  return __uint_as_float(u);
}
constexpr unsigned MONO_NEG_INF = 0x007FFFFFu;

// ---- bf16 helpers ----
__device__ __forceinline__ unsigned short f2bf(float f) {
  unsigned u = __float_as_uint(f);
  unsigned r = (u + 0x7FFFu + ((u >> 16) & 1u)) >> 16;  // RNE
  return (unsigned short)r;
}
__device__ __forceinline__ float bf2f(unsigned short h) {
  return __uint_as_float((unsigned)h << 16);
}
__device__ __forceinline__ float bflo(unsigned u) { return __uint_as_float(u << 16); }
__device__ __forceinline__ float bfhi(unsigned u) { return __uint_as_float(u & 0xFFFF0000u); }

// ---- build transposed bf16 hi/lo weights ----
__global__ __launch_bounds__(256) void build_wT(const float* __restrict__ W_root,
                                                const float* __restrict__ W_rel,
                                                const float* __restrict__ W_gat,
                                                unsigned short* __restrict__ WbT_hi,
                                                unsigned short* __restrict__ WbT_lo,
                                                unsigned short* __restrict__ WgT_hi,
                                                unsigned short* __restrict__ WgT_lo) {
  int i = blockIdx.x * 256 + threadIdx.x;
  if (i < MBIG * F_IN) {               // WbigT[c][k]
    int c = i / F_IN, k = i % F_IN;
    float w = (c < H1) ? W_root[k * H1 + c]
                       : W_rel[((size_t)(((c - H1) >> 6) * F_IN + k)) * H1 + ((c - H1) & 63)];
    unsigned short hi = f2bf(w);
    WbT_hi[i] = hi;
    WbT_lo[i] = f2bf(w - bf2f(hi));
  } else {
    int j = i - MBIG * F_IN;
    if (j < HOUT * H1) {               // WgatT[c][k]
      int c = j / H1, k = j % H1;
      float w = W_gat[k * HOUT + c];
      unsigned short hi = f2bf(w);
      WgT_hi[j] = hi;
      WgT_lo[j] = f2bf(w - bf2f(hi));
    }
  }
}

// ---- split-bf16 MFMA GEMM, 2D grid: block = 64 rows x 64 cols.
//      A f32 [N,K]; BT hi/lo bf16 [M,K]; out bf16 (and/or f32). ----
template <int K>
__global__ __launch_bounds__(256) void gemm_mfma(const float* __restrict__ A,
                                                 const unsigned short* __restrict__ BT_hi,
                                                 const unsigned short* __restrict__ BT_lo,
                                                 float* __restrict__ C,
                                                 unsigned short* __restrict__ Cbf,
                                                 int N, int M) {
  constexpr int Kp = K + 8;
  __shared__ unsigned short Ahi[64 * Kp];
  __shared__ unsigned short Alo[64 * Kp];
  const int tid = threadIdx.x;
  const int rowBase = blockIdx.x * 64;
  const int colBase = blockIdx.y * 64;
  // stage A tile f32 -> bf16 hi/lo
  constexpr int KQ = K >> 2;           // float4 per row
  constexpr int slots = 64 * KQ;
  for (int s = tid; s < slots; s += 256) {
    int r = s / KQ, c4 = (s % KQ) * 4;
    int gr = rowBase + r;
    float4 v = make_float4(0.f, 0.f, 0.f, 0.f);
    if (gr < N) v = *reinterpret_cast<const float4*>(&A[(size_t)gr * K + c4]);
    ushort4 hi, lo;
    hi.x = f2bf(v.x); lo.x = f2bf(v.x - bf2f(hi.x));
    hi.y = f2bf(v.y); lo.y = f2bf(v.y - bf2f(hi.y));
    hi.z = f2bf(v.z); lo.z = f2bf(v.z - bf2f(hi.z));
    hi.w = f2bf(v.w); lo.w = f2bf(v.w - bf2f(hi.w));
    *reinterpret_cast<ushort4*>(&Ahi[r * Kp + c4]) = hi;
    *reinterpret_cast<ushort4*>(&Alo[r * Kp + c4]) = lo;
  }
  __syncthreads();
  const int wv = tid >> 6, lane = tid & 63;
  const int wr = (wv >> 1) * 32, wc = (wv & 1) * 32;
  const int lrow = lane & 15, lkc = lane >> 4;
  f32x4 acc[2][2] = {};
#pragma unroll
  for (int ks = 0; ks < K; ks += 32) {
    bf16x8 ah[2], al[2], bh[2], bl[2];
#pragma unroll
    for (int fr = 0; fr < 2; ++fr) {
      int r = wr + fr * 16 + lrow;
      ah[fr] = *reinterpret_cast<const bf16x8*>(&Ahi[r * Kp + ks + lkc * 8]);
      al[fr] = *reinterpret_cast<const bf16x8*>(&Alo[r * Kp + ks + lkc * 8]);
    }
#pragma unroll
    for (int fc = 0; fc < 2; ++fc) {
      int c = colBase + wc + fc * 16 + lrow;
      bh[fc] = *reinterpret_cast<const bf16x8*>(&BT_hi[(size_t)c * K + ks + lkc * 8]);
      bl[fc] = *reinterpret_cast<const bf16x8*>(&BT_lo[(size_t)c * K + ks + lkc * 8]);
    }
#pragma unroll
    for (int fr = 0; fr < 2; ++fr)
#pragma unroll
      for (int fc = 0; fc < 2; ++fc) {
        acc[fr][fc] = __builtin_amdgcn_mfma_f32_16x16x32_bf16(ah[fr], bh[fc], acc[fr][fc], 0, 0, 0);
        acc[fr][fc] = __builtin_amdgcn_mfma_f32_16x16x32_bf16(ah[fr], bl[fc], acc[fr][fc], 0, 0, 0);
        acc[fr][fc] = __builtin_amdgcn_mfma_f32_16x16x32_bf16(al[fr], bh[fc], acc[fr][fc], 0, 0, 0);
      }
  }
#pragma unroll
  for (int fr = 0; fr < 2; ++fr) {
#pragma unroll
    for (int i = 0; i < 4; ++i) {
      int row = rowBase + wr + fr * 16 + lkc * 4 + i;
      if (row < N) {
#pragma unroll
        for (int fc = 0; fc < 2; ++fc) {
          int col = colBase + wc + fc * 16 + lrow;
          float v = acc[fr][fc][i];
          if (C) C[(size_t)row * M + col] = v;
          if (Cbf) Cbf[(size_t)row * M + col] = f2bf(v);
        }
      }
    }
  }
}

// ---- CSR build: histogram of dst ----
__global__ __launch_bounds__(256) void k_hist(const int* __restrict__ dst,
                                              int* __restrict__ deg) {
  int e = blockIdx.x * 256 + threadIdx.x;
  if (e < N_EDGES) atomicAdd(&deg[dst[e]], 1);
}

// ---- scan stage 1: per-block sums ----
__global__ __launch_bounds__(256) void k_s1(const int* __restrict__ deg,
                                            int* __restrict__ bsum) {
  __shared__ int ss[256];
  int t = threadIdx.x;
  int i = blockIdx.x * 256 + t;
  ss[t] = (i < N_NODES) ? deg[i] : 0;
  __syncthreads();
  for (int d = 128; d > 0; d >>= 1) {
    if (t < d) ss[t] += ss[t + d];
    __syncthreads();
  }
  if (t == 0) bsum[blockIdx.x] = ss[0];
}

// ---- scan stage 2: exclusive scan of block sums ----
__global__ __launch_bounds__(256) void k_s2(const int* __restrict__ bsum,
                                            int* __restrict__ bbase,
                                            int* __restrict__ off) {
  __shared__ int ss[256];
  int t = threadIdx.x;
  int v = (t < NBLK) ? bsum[t] : 0;
  ss[t] = v;
  __syncthreads();
  for (int d = 1; d < 256; d <<= 1) {
    int u = (t >= d) ? ss[t - d] : 0;
    __syncthreads();
    ss[t] += u;
    __syncthreads();
  }
  if (t < NBLK) bbase[t] = ss[t] - v;
  if (t == NBLK - 1) off[N_NODES] = ss[t];
}

// ---- scan stage 3: block-local scan + base ----
__global__ __launch_bounds__(256) void k_s3(const int* __restrict__ deg,
                                            const int* __restrict__ bbase,
                                            int* __restrict__ off,
                                            int* __restrict__ cursor) {
  __shared__ int ss[256];
  int t = threadIdx.x;
  int i = blockIdx.x * 256 + t;
  int v = (i < N_NODES) ? deg[i] : 0;
  ss[t] = v;
  __syncthreads();
  for (int d = 1; d < 256; d <<= 1) {
    int u = (t >= d) ? ss[t - d] : 0;
    __syncthreads();
    ss[t] += u;
    __syncthreads();
  }
  if (i < N_NODES) {
    int o = bbase[blockIdx.x] + ss[t] - v;
    off[i] = o;
    cursor[i] = o;
  }
}

// ---- CSR fill: packed (src | etype<<16) ----
__global__ __launch_bounds__(256) void k_fill(const int* __restrict__ src,
                                              const int* __restrict__ dst,
                                              const int* __restrict__ etype,
                                              int* __restrict__ cursor,
                                              int* __restrict__ eprep) {
  int e = blockIdx.x * 256 + threadIdx.x;
  if (e >= N_EDGES) return;
  int pos = atomicAdd(&cursor[dst[e]], 1);
  eprep[pos] = src[e] | (etype[e] << 16);
}

// ---- RGCN: gather from bf16 xt; wave/node; 2 edges/iter (half-wave each);
//      lane handles a channel pair via u32 loads; x2 unroll = 4 gathers live ----
__global__ __launch_bounds__(256) void rgcn_gather(const unsigned short* __restrict__ xtbf,
                                                   const int* __restrict__ off,
                                                   const int* __restrict__ eprep,
                                                   const float* __restrict__ b_rgcn,
                                                   float* __restrict__ h) {
  int wid = (blockIdx.x * 256 + threadIdx.x) >> 6;
  int lane = threadIdx.x & 63;
  int half = lane >> 5;        // 0: even-position edges, 1: odd
  int cp = lane & 31;          // channel pair (ch 2cp, 2cp+1)
  int start = off[wid], end = off[wid + 1];
  float a0x=0.f,a0y=0.f,a1x=0.f,a1y=0.f,a2x=0.f,a2y=0.f,a3x=0.f,a3y=0.f;
  int c0=0,c1=0,c2=0,c3=0;
  int niter = (end - start + 1) >> 1;  // wave-uniform
  for (int t = 0; t < niter; t += 2) {
    int idx0 = start + 2 * t + half;
    int idx1 = idx0 + 2;
    int p0 = (idx0 < end) ? eprep[idx0] : 0x70000;  // sentinel r=7
    int p1 = (idx1 < end) ? eprep[idx1] : 0x70000;
    int s0 = p0 & 0xFFFF, r0 = p0 >> 16;
    int s1 = p1 & 0xFFFF, r1 = p1 >> 16;
    unsigned u0 = *reinterpret_cast<const unsigned*>(
        &xtbf[(size_t)s0 * MBIG + H1 + (r0 << 6) + cp * 2]);
    unsigned u1 = *reinterpret_cast<const unsigned*>(
        &xtbf[(size_t)s1 * MBIG + H1 + (r1 << 6) + cp * 2]);
    float v0x = bflo(u0), v0y = bfhi(u0);
    float v1x = bflo(u1), v1y = bfhi(u1);
    a0x += (r0==0)?v0x:0.f; a0y += (r0==0)?v0y:0.f; c0 += (r0==0);
    a1x += (r0==1)?v0x:0.f; a1y += (r0==1)?v0y:0.f; c1 += (r0==1);
    a2x += (r0==2)?v0x:0.f; a2y += (r0==2)?v0y:0.f; c2 += (r0==2);
    a3x += (r0==3)?v0x:0.f; a3y += (r0==3)?v0y:0.f; c3 += (r0==3);
    a0x += (r1==0)?v1x:0.f; a0y += (r1==0)?v1y:0.f; c0 += (r1==0);
    a1x += (r1==1)?v1x:0.f; a1y += (r1==1)?v1y:0.f; c1 += (r1==1);
    a2x += (r1==2)?v1x:0.f; a2y += (r1==2)?v1y:0.f; c2 += (r1==2);
    a3x += (r1==3)?v1x:0.f; a3y += (r1==3)?v1y:0.f; c3 += (r1==3);
  }
  // cross-half combine
  a0x += __shfl_xor(a0x, 32); a0y += __shfl_xor(a0y, 32);
  a1x += __shfl_xor(a1x, 32); a1y += __shfl_xor(a1y, 32);
  a2x += __shfl_xor(a2x, 32); a2y += __shfl_xor(a2y, 32);
  a3x += __shfl_xor(a3x, 32); a3y += __shfl_xor(a3y, 32);
  c0 += __shfl_xor(c0, 32); c1 += __shfl_xor(c1, 32);
  c2 += __shfl_xor(c2, 32); c3 += __shfl_xor(c3, 32);
  if (half == 0) {
    unsigned ur = *reinterpret_cast<const unsigned*>(&xtbf[(size_t)wid * MBIG + cp * 2]);
    float2 bb = *reinterpret_cast<const float2*>(&b_rgcn[cp * 2]);
    float i0 = 1.0f / (float)max(c0, 1);
    float i1 = 1.0f / (float)max(c1, 1);
    float i2 = 1.0f / (float)max(c2, 1);
    float i3 = 1.0f / (float)max(c3, 1);
    float vx = bflo(ur) + bb.x + a0x * i0 + a1x * i1 + a2x * i2 + a3x * i3;
    float vy = bfhi(ur) + bb.y + a0y * i0 + a1y * i1 + a2y * i2 + a3y * i3;
    *reinterpret_cast<float2*>(&h[(size_t)wid * H1 + cp * 2]) =
        make_float2(fmaxf(vx, 0.f), fmaxf(vy, 0.f));
  }
}

// ---- attention coefficients from bf16 g, LDS-staged ----
__global__ __launch_bounds__(256) void gat_att(const unsigned short* __restrict__ gbf,
                                               const float* __restrict__ att_src,
                                               const float* __restrict__ att_dst,
                                               float* __restrict__ a_s,
                                               float* __restrict__ a_d) {
  __shared__ float gs[64][129];
  __shared__ float asrc[HOUT], adst[HOUT];
  int t = threadIdx.x;
  if (t < HOUT) { asrc[t] = att_src[t]; adst[t] = att_dst[t]; }
  int nb = blockIdx.x * 64;
#pragma unroll
  for (int it = 0; it < 8; ++it) {
    int idx = it * 256 + t;
    int r = idx >> 5, c4 = (idx & 31) * 4;
    int gn = nb + r;
    uint2 v = make_uint2(0u, 0u);
    if (gn < N_NODES)
      v = *reinterpret_cast<const uint2*>(&gbf[(size_t)gn * HOUT + c4]);
    gs[r][c4 + 0] = bflo(v.x); gs[r][c4 + 1] = bfhi(v.x);
    gs[r][c4 + 2] = bflo(v.y); gs[r][c4 + 3] = bfhi(v.y);
  }
  __syncthreads();
  int n = t & 63, hh = t >> 6;
  float s = 0.f, d = 0.f;
#pragma unroll
  for (int k = 0; k < D_H; ++k) {
    float gv = gs[n][hh * D_H + k];
    s += gv * asrc[hh * D_H + k];
    d += gv * adst[hh * D_H + k];
  }
  if (nb + n < N_NODES) {
    a_s[(size_t)(nb + n) * 4 + hh] = s;
    a_d[(size_t)(nb + n) * 4 + hh] = d;
  }
}

// ---- GAT: softmax attention aggregation; wave/node; no max pass ----
__global__ __launch_bounds__(256) void gat_gather(const unsigned short* __restrict__ gbf,
                                                  const float* __restrict__ a_s,
                                                  const float* __restrict__ a_d,
                                                  const int* __restrict__ off,
                                                  const int* __restrict__ eprep,
                                                  const float* __restrict__ b_gat,
                                                  float* __restrict__ o) {
  int wid = (blockIdx.x * 256 + threadIdx.x) >> 6;
  int lane = threadIdx.x & 63;
  int start = off[wid], end = off[wid + 1];
  int hh = lane >> 4;
  float4 ad4 = *reinterpret_cast<const float4*>(a_d + (size_t)wid * 4);
  float adh = (hh == 0) ? ad4.x : (hh == 1) ? ad4.y : (hh == 2) ? ad4.z : ad4.w;
  float ox = 0.f, oy = 0.f, den = 0.f;
  int i = start;
  for (; i + 4 <= end; i += 4) {
    int p0 = eprep[i], p1 = eprep[i + 1], p2 = eprep[i + 2], p3 = eprep[i + 3];
    int s0 = p0 & 0xFFFF, s1 = p1 & 0xFFFF, s2 = p2 & 0xFFFF, s3 = p3 & 0xFFFF;
    float as0 = a_s[(size_t)s0 * 4 + hh];
    float as1 = a_s[(size_t)s1 * 4 + hh];
    float as2 = a_s[(size_t)s2 * 4 + hh];
    float as3 = a_s[(size_t)s3 * 4 + hh];
    unsigned u0 = *reinterpret_cast<const unsigned*>(&gbf[(size_t)s0 * HOUT + lane * 2]);
    unsigned u1 = *reinterpret_cast<const unsigned*>(&gbf[(size_t)s1 * HOUT + lane * 2]);
    unsigned u2 = *reinterpret_cast<const unsigned*>(&gbf[(size_t)s2 * HOUT + lane * 2]);
    unsigned u3 = *reinterpret_cast<const unsigned*>(&gbf[(size_t)s3 * HOUT + lane * 2]);
    float e0 = as0 + adh; e0 = (e0 > 0.f) ? e0 : 0.2f * e0;
    float e1 = as1 + adh; e1 = (e1 > 0.f) ? e1 : 0.2f * e1;
    float e2 = as2 + adh; e2 = (e2 > 0.f) ? e2 : 0.2f * e2;
    float e3 = as3 + adh; e3 = (e3 > 0.f) ? e3 : 0.2f * e3;
    float x0 = __expf(e0), x1 = __expf(e1), x2 = __expf(e2), x3 = __expf(e3);
    den += x0 + x1 + x2 + x3;
    ox += x0 * bflo(u0) + x1 * bflo(u1) + x2 * bflo(u2) + x3 * bflo(u3);
    oy += x0 * bfhi(u0) + x1 * bfhi(u1) + x2 * bfhi(u2) + x3 * bfhi(u3);
  }
  for (; i < end; ++i) {
    int p = eprep[i];
    int s = p & 0xFFFF;
    float as = a_s[(size_t)s * 4 + hh];
    unsigned u = *reinterpret_cast<const unsigned*>(&gbf[(size_t)s * HOUT + lane * 2]);
    float e = as + adh; e = (e > 0.f) ? e : 0.2f * e;
    float ex = __expf(e);
    den += ex;
    ox += ex * bflo(u);
    oy += ex * bfhi(u);
  }
  float dinv = (den > 0.f) ? (1.0f / den) : 0.f;
  float2 bg = *reinterpret_cast<const float2*>(b_gat + lane * 2);
  float vx = ox * dinv + bg.x; vx = (vx > 0.f) ? vx : 0.01f * vx;
  float vy = oy * dinv + bg.y; vy = (vy > 0.f) ? vy : 0.01f * vy;
  *reinterpret_cast<float2*>(o + (size_t)wid * HOUT + lane * 2) = make_float2(vx, vy);
}

// ---- init mono buffer ----
__global__ __launch_bounds__(256) void init_mono(unsigned* __restrict__ p, int count) {
  int i = blockIdx.x * 256 + threadIdx.x;
  if (i < count) p[i] = MONO_NEG_INF;
}

// ---- head: z = leaky(o @ W1 + b1); per-graph max pool ----
__global__ __launch_bounds__(256) void final_z(const float* __restrict__ o,
                                               const float* __restrict__ W1,
                                               const float* __restrict__ b1,
                                               const int* __restrict__ batch,
                                               unsigned* __restrict__ p_mono) {
  __shared__ float os[64][129];
  __shared__ float w1s[HOUT * 16];
  __shared__ unsigned sp[N_GRAPHS * 16];
  int t = threadIdx.x;
  for (int i = t; i < N_GRAPHS * 16; i += 256) sp[i] = MONO_NEG_INF;
  for (int i = t; i < HOUT * 16; i += 256) w1s[i] = W1[i];
  int nb = blockIdx.x * 64;
#pragma unroll
  for (int it = 0; it < 8; ++it) {
    int idx = it * 256 + t;
    int r = idx >> 5, c4 = (idx & 31) * 4;
    int gn = nb + r;
    float4 v = make_float4(0.f, 0.f, 0.f, 0.f);
    if (gn < N_NODES) v = *reinterpret_cast<const float4*>(&o[(size_t)gn * HOUT + c4]);
    os[r][c4 + 0] = v.x; os[r][c4 + 1] = v.y;
    os[r][c4 + 2] = v.z; os[r][c4 + 3] = v.w;
  }
  __syncthreads();
  int n = t >> 2, jg = (t & 3) * 4;
  float z0 = b1[jg], z1 = b1[jg + 1], z2 = b1[jg + 2], z3 = b1[jg + 3];
#pragma unroll 8
  for (int k = 0; k < HOUT; ++k) {
    float v = os[n][k];
    float4 w = *reinterpret_cast<const float4*>(&w1s[k * 16 + jg]);
    z0 += v * w.x; z1 += v * w.y; z2 += v * w.z; z3 += v * w.w;
  }
  if (nb + n < N_NODES) {
    int b = batch[nb + n];
    float zz;
    zz = (z0 > 0.f) ? z0 : 0.01f * z0; atomicMax(&sp[b * 16 + jg + 0], f2mono(zz));
    zz = (z1 > 0.f) ? z1 : 0.01f * z1; atomicMax(&sp[b * 16 + jg + 1], f2mono(zz));
    zz = (z2 > 0.f) ? z2 : 0.01f * z2; atomicMax(&sp[b * 16 + jg + 2], f2mono(zz));
    zz = (z3 > 0.f) ? z3 : 0.01f * z3; atomicMax(&sp[b * 16 + jg + 3], f2mono(zz));
  }
  __syncthreads();
  for (int i = t; i < N_GRAPHS * 16; i += 256) {
    unsigned v = sp[i];
    if (v != MONO_NEG_INF) atomicMax(p_mono + i, v);
  }
}

// ---- y = p @ W2 + b2 ----
__global__ void final_y(const unsigned* __restrict__ p_mono,
                        const float* __restrict__ W2,
                        const float* __restrict__ b2,
                        float* __restrict__ y) {
  int gr = threadIdx.x;
  if (gr >= N_GRAPHS) return;
  float acc = b2[0];
#pragma unroll
  for (int k = 0; k < 16; ++k) acc += mono2f(p_mono[gr * 16 + k]) * W2[k];
  y[gr] = acc;
}

extern "C" void kernel_launch(void* const* d_in, const int* in_sizes, int n_in,
                              void* d_out, int out_size, void* d_ws, size_t ws_size,
                              hipStream_t stream) {
  const float* x       = (const float*)d_in[0];
  const int*   eidx    = (const int*)d_in[1];
  const int*   etype   = (const int*)d_in[2];
  const int*   batch   = (const int*)d_in[3];
  const float* W_rel   = (const float*)d_in[4];
  const float* W_root  = (const float*)d_in[5];
  const float* b_rgcn  = (const float*)d_in[6];
  const float* W_gat   = (const float*)d_in[7];
  const float* att_src = (const float*)d_in[8];
  const float* att_dst = (const float*)d_in[9];
  const float* b_gat   = (const float*)d_in[10];
  const float* W1      = (const float*)d_in[11];
  const float* b1      = (const float*)d_in[12];
  const float* W2      = (const float*)d_in[13];
  const float* b2      = (const float*)d_in[14];
  float* y = (float*)d_out;

  const int* src = eidx;
  const int* dst = eidx + N_EDGES;

  float* ws = (float*)d_ws;
  const size_t OFF_XTBF= 0;           //  8,000,000 f = 16M u16: xt bf16 [N,320]
  const size_t OFF_GBF = 0;           //  g bf16 [N,128] (reuses xtbf after rgcn)
  const size_t OFF_O   = 8000000;     //  6,400,000  o [N,128] f32
  const size_t OFF_H   = 14400000;    //  3,200,000  h [N,64] f32
  const size_t OFF_AS  = 17600000;    //    200,000  a_src
  const size_t OFF_AD  = 17800000;    //    200,000  a_dst
  const size_t OFF_PM  = 18000000;    //      1,024  pool max (mono u32)
  const size_t OFF_DEG = 18002000;    //     50,000  deg (int)
  const size_t OFF_OFFS= 18052000;    //     50,001  off (int)
  const size_t OFF_CUR = 18102016;    //     50,000  cursor (int)
  const size_t OFF_EP  = 18152016;    //    800,000  eprep (int)
  const size_t OFF_BS  = 18952016;    //        196
  const size_t OFF_BB  = 18952212;    //        196
  const size_t OFF_WBH = 18952512;    //     20,480  WbigT_hi (40960 u16)
  const size_t OFF_WBL = 18972992;    //     20,480  WbigT_lo
  const size_t OFF_WGH = 18993472;    //      4,096  WgatT_hi (8192 u16)
  const size_t OFF_WGL = 18997568;    //      4,096  WgatT_lo
  const size_t TOTAL_F = 19001664;
  if (ws_size < TOTAL_F * sizeof(float)) return;

  unsigned short* xtbf = (unsigned short*)(ws + OFF_XTBF);
  unsigned short* gbf  = (unsigned short*)(ws + OFF_GBF);
  float* o     = ws + OFF_O;
  float* h     = ws + OFF_H;
  float* a_s   = ws + OFF_AS;
  float* a_d   = ws + OFF_AD;
  unsigned* pm = (unsigned*)(ws + OFF_PM);
  int* deg     = (int*)(ws + OFF_DEG);
  int* offs    = (int*)(ws + OFF_OFFS);
  int* cursor  = (int*)(ws + OFF_CUR);
  int* eprep   = (int*)(ws + OFF_EP);
  int* bsum    = (int*)(ws + OFF_BS);
  int* bbase   = (int*)(ws + OFF_BB);
  unsigned short* wbt_hi = (unsigned short*)(ws + OFF_WBH);
  unsigned short* wbt_lo = (unsigned short*)(ws + OFF_WBL);
  unsigned short* wgt_hi = (unsigned short*)(ws + OFF_WGH);
  unsigned short* wgt_lo = (unsigned short*)(ws + OFF_WGL);

  // CSR build
  hipMemsetAsync(deg, 0, N_NODES * sizeof(int), stream);
  k_hist<<<(N_EDGES + 255) / 256, 256, 0, stream>>>(dst, deg);
  k_s1<<<NBLK, 256, 0, stream>>>(deg, bsum);
  k_s2<<<1, 256, 0, stream>>>(bsum, bbase, offs);
  k_s3<<<NBLK, 256, 0, stream>>>(deg, bbase, offs, cursor);
  k_fill<<<(N_EDGES + 255) / 256, 256, 0, stream>>>(src, dst, etype, cursor, eprep);

  // transposed bf16 hi/lo weights
  build_wT<<<(MBIG * F_IN + HOUT * H1 + 255) / 256, 256, 0, stream>>>(
      W_root, W_rel, W_gat, wbt_hi, wbt_lo, wgt_hi, wgt_lo);

  // xt(bf16) = x @ [W_root | W_rel]  (split-bf16 MFMA; 2D grid)
  {
    dim3 grid((N_NODES + 63) / 64, MBIG / 64);
    gemm_mfma<128><<<grid, 256, 0, stream>>>(x, wbt_hi, wbt_lo, nullptr, xtbf,
                                             N_NODES, MBIG);
  }

  // RGCN gather -> h (f32)
  rgcn_gather<<<N_NODES / 4, 256, 0, stream>>>(xtbf, offs, eprep, b_rgcn, h);

  // g(bf16) = h @ W_gat  (xtbf region dead now)
  {
    dim3 grid((N_NODES + 63) / 64, HOUT / 64);
    gemm_mfma<64><<<grid, 256, 0, stream>>>(h, wgt_hi, wgt_lo, nullptr, gbf,
                                            N_NODES, HOUT);
  }

  // attention coefficients (bf16 g)
  gat_att<<<(N_NODES + 63) / 64, 256, 0, stream>>>(gbf, att_src, att_dst, a_s, a_d);

  // GAT gather -> o (normalized + bias + leaky)
  gat_gather<<<N_NODES / 4, 256, 0, stream>>>(gbf, a_s, a_d, offs, eprep, b_gat, o);

  // head + per-graph max pool
  init_mono<<<(N_GRAPHS * 16 + 255) / 256, 256, 0, stream>>>(pm, N_GRAPHS * 16);
  final_z<<<(N_NODES + 63) / 64, 256, 0, stream>>>(o, W1, b1, batch, pm);
  final_y<<<1, 64, 0, stream>>>(pm, W2, b2, y);
}

// Round 7
// 270.163 us; speedup vs baseline: 9.0687x; 1.0230x over previous
//
#include <hip/hip_runtime.h>
#include <hip/hip_bf16.h>

constexpr int N_NODES = 50000;
constexpr int N_EDGES = 800000;
constexpr int F_IN = 128;
constexpr int H1 = 64;
constexpr int HEADS = 4;
constexpr int D_H = 32;
constexpr int HOUT = HEADS * D_H;       // 128
constexpr int N_REL = 4;
constexpr int N_GRAPHS = 64;
constexpr int MBIG = H1 * (1 + N_REL);  // 320
constexpr int NBLK = (N_NODES + 255) / 256;  // 196

typedef __attribute__((ext_vector_type(8))) short bf16x8;
typedef __attribute__((ext_vector_type(4))) float f32x4;

// ---- monotonic float<->uint for atomicMax on floats ----
__device__ __forceinline__ unsigned f2mono(float f) {
  unsigned u = __float_as_uint(f);
  return (u & 0x80000000u) ? ~u : (u | 0x80000000u);
}
__device__ __forceinline__ float mono2f(unsigned m) {
  unsigned u = (m & 0x80000000u) ? (m & 0x7FFFFFFFu) : ~m;
  return __uint_as_float(u);
}
constexpr unsigned MONO_NEG_INF = 0x007FFFFFu;

// ---- bf16 helpers ----
__device__ __forceinline__ unsigned short f2bf(float f) {
  unsigned u = __float_as_uint(f);
  unsigned r = (u + 0x7FFFu + ((u >> 16) & 1u)) >> 16;  // RNE
  return (unsigned short)r;
}
__device__ __forceinline__ float bf2f(unsigned short h) {
  return __uint_as_float((unsigned)h << 16);
}
__device__ __forceinline__ float bflo(unsigned u) { return __uint_as_float(u << 16); }
__device__ __forceinline__ float bfhi(unsigned u) { return __uint_as_float(u & 0xFFFF0000u); }

// ---- build transposed bf16 hi/lo weights ----
__global__ __launch_bounds__(256) void build_wT(const float* __restrict__ W_root,
                                                const float* __restrict__ W_rel,
                                                const float* __restrict__ W_gat,
                                                unsigned short* __restrict__ WbT_hi,
                                                unsigned short* __restrict__ WbT_lo,
                                                unsigned short* __restrict__ WgT_hi,
                                                unsigned short* __restrict__ WgT_lo) {
  int i = blockIdx.x * 256 + threadIdx.x;
  if (i < MBIG * F_IN) {               // WbigT[c][k]
    int c = i / F_IN, k = i % F_IN;
    float w = (c < H1) ? W_root[k * H1 + c]
                       : W_rel[((size_t)(((c - H1) >> 6) * F_IN + k)) * H1 + ((c - H1) & 63)];
    unsigned short hi = f2bf(w);
    WbT_hi[i] = hi;
    WbT_lo[i] = f2bf(w - bf2f(hi));
  } else {
    int j = i - MBIG * F_IN;
    if (j < HOUT * H1) {               // WgatT[c][k]
      int c = j / H1, k = j % H1;
      float w = W_gat[k * HOUT + c];
      unsigned short hi = f2bf(w);
      WgT_hi[j] = hi;
      WgT_lo[j] = f2bf(w - bf2f(hi));
    }
  }
}

// ---- split-bf16 MFMA GEMM, 2D grid: block = 64 rows x 64 cols ----
template <int K>
__global__ __launch_bounds__(256) void gemm_mfma(const float* __restrict__ A,
                                                 const unsigned short* __restrict__ BT_hi,
                                                 const unsigned short* __restrict__ BT_lo,
                                                 float* __restrict__ C,
                                                 unsigned short* __restrict__ Cbf,
                                                 int N, int M) {
  constexpr int Kp = K + 8;
  __shared__ unsigned short Ahi[64 * Kp];
  __shared__ unsigned short Alo[64 * Kp];
  const int tid = threadIdx.x;
  const int rowBase = blockIdx.x * 64;
  const int colBase = blockIdx.y * 64;
  constexpr int KQ = K >> 2;
  constexpr int slots = 64 * KQ;
  for (int s = tid; s < slots; s += 256) {
    int r = s / KQ, c4 = (s % KQ) * 4;
    int gr = rowBase + r;
    float4 v = make_float4(0.f, 0.f, 0.f, 0.f);
    if (gr < N) v = *reinterpret_cast<const float4*>(&A[(size_t)gr * K + c4]);
    ushort4 hi, lo;
    hi.x = f2bf(v.x); lo.x = f2bf(v.x - bf2f(hi.x));
    hi.y = f2bf(v.y); lo.y = f2bf(v.y - bf2f(hi.y));
    hi.z = f2bf(v.z); lo.z = f2bf(v.z - bf2f(hi.z));
    hi.w = f2bf(v.w); lo.w = f2bf(v.w - bf2f(hi.w));
    *reinterpret_cast<ushort4*>(&Ahi[r * Kp + c4]) = hi;
    *reinterpret_cast<ushort4*>(&Alo[r * Kp + c4]) = lo;
  }
  __syncthreads();
  const int wv = tid >> 6, lane = tid & 63;
  const int wr = (wv >> 1) * 32, wc = (wv & 1) * 32;
  const int lrow = lane & 15, lkc = lane >> 4;
  f32x4 acc[2][2] = {};
#pragma unroll
  for (int ks = 0; ks < K; ks += 32) {
    bf16x8 ah[2], al[2], bh[2], bl[2];
#pragma unroll
    for (int fr = 0; fr < 2; ++fr) {
      int r = wr + fr * 16 + lrow;
      ah[fr] = *reinterpret_cast<const bf16x8*>(&Ahi[r * Kp + ks + lkc * 8]);
      al[fr] = *reinterpret_cast<const bf16x8*>(&Alo[r * Kp + ks + lkc * 8]);
    }
#pragma unroll
    for (int fc = 0; fc < 2; ++fc) {
      int c = colBase + wc + fc * 16 + lrow;
      bh[fc] = *reinterpret_cast<const bf16x8*>(&BT_hi[(size_t)c * K + ks + lkc * 8]);
      bl[fc] = *reinterpret_cast<const bf16x8*>(&BT_lo[(size_t)c * K + ks + lkc * 8]);
    }
#pragma unroll
    for (int fr = 0; fr < 2; ++fr)
#pragma unroll
      for (int fc = 0; fc < 2; ++fc) {
        acc[fr][fc] = __builtin_amdgcn_mfma_f32_16x16x32_bf16(ah[fr], bh[fc], acc[fr][fc], 0, 0, 0);
        acc[fr][fc] = __builtin_amdgcn_mfma_f32_16x16x32_bf16(ah[fr], bl[fc], acc[fr][fc], 0, 0, 0);
        acc[fr][fc] = __builtin_amdgcn_mfma_f32_16x16x32_bf16(al[fr], bh[fc], acc[fr][fc], 0, 0, 0);
      }
  }
#pragma unroll
  for (int fr = 0; fr < 2; ++fr) {
#pragma unroll
    for (int i = 0; i < 4; ++i) {
      int row = rowBase + wr + fr * 16 + lkc * 4 + i;
      if (row < N) {
#pragma unroll
        for (int fc = 0; fc < 2; ++fc) {
          int col = colBase + wc + fc * 16 + lrow;
          float v = acc[fr][fc][i];
          if (C) C[(size_t)row * M + col] = v;
          if (Cbf) Cbf[(size_t)row * M + col] = f2bf(v);
        }
      }
    }
  }
}

// ---- CSR build: histogram of dst + per-edge rank (coalesced store) ----
__global__ __launch_bounds__(256) void k_hist(const int* __restrict__ dst,
                                              int* __restrict__ deg,
                                              int* __restrict__ rank) {
  int e = blockIdx.x * 256 + threadIdx.x;
  if (e < N_EDGES) rank[e] = atomicAdd(&deg[dst[e]], 1);
}

// ---- scan stage 1: per-block sums ----
__global__ __launch_bounds__(256) void k_s1(const int* __restrict__ deg,
                                            int* __restrict__ bsum) {
  __shared__ int ss[256];
  int t = threadIdx.x;
  int i = blockIdx.x * 256 + t;
  ss[t] = (i < N_NODES) ? deg[i] : 0;
  __syncthreads();
  for (int d = 128; d > 0; d >>= 1) {
    if (t < d) ss[t] += ss[t + d];
    __syncthreads();
  }
  if (t == 0) bsum[blockIdx.x] = ss[0];
}

// ---- scan stage 2: exclusive scan of block sums ----
__global__ __launch_bounds__(256) void k_s2(const int* __restrict__ bsum,
                                            int* __restrict__ bbase,
                                            int* __restrict__ off) {
  __shared__ int ss[256];
  int t = threadIdx.x;
  int v = (t < NBLK) ? bsum[t] : 0;
  ss[t] = v;
  __syncthreads();
  for (int d = 1; d < 256; d <<= 1) {
    int u = (t >= d) ? ss[t - d] : 0;
    __syncthreads();
    ss[t] += u;
    __syncthreads();
  }
  if (t < NBLK) bbase[t] = ss[t] - v;
  if (t == NBLK - 1) off[N_NODES] = ss[t];
}

// ---- scan stage 3: block-local scan + base ----
__global__ __launch_bounds__(256) void k_s3(const int* __restrict__ deg,
                                            const int* __restrict__ bbase,
                                            int* __restrict__ off) {
  __shared__ int ss[256];
  int t = threadIdx.x;
  int i = blockIdx.x * 256 + t;
  int v = (i < N_NODES) ? deg[i] : 0;
  ss[t] = v;
  __syncthreads();
  for (int d = 1; d < 256; d <<= 1) {
    int u = (t >= d) ? ss[t - d] : 0;
    __syncthreads();
    ss[t] += u;
    __syncthreads();
  }
  if (i < N_NODES) off[i] = bbase[blockIdx.x] + ss[t] - v;
}

// ---- CSR fill: atomic-free — pos = off[dst] + rank; scatter store ----
__global__ __launch_bounds__(256) void k_fill(const int* __restrict__ src,
                                              const int* __restrict__ dst,
                                              const int* __restrict__ etype,
                                              const int* __restrict__ off,
                                              const int* __restrict__ rank,
                                              int* __restrict__ eprep) {
  int e = blockIdx.x * 256 + threadIdx.x;
  if (e >= N_EDGES) return;
  int pos = off[dst[e]] + rank[e];
  eprep[pos] = src[e] | (etype[e] << 16);
}

// ---- RGCN: gather from bf16 xt; wave/node; 2 edges/iter, x2 unroll ----
__global__ __launch_bounds__(256) void rgcn_gather(const unsigned short* __restrict__ xtbf,
                                                   const int* __restrict__ off,
                                                   const int* __restrict__ eprep,
                                                   const float* __restrict__ b_rgcn,
                                                   float* __restrict__ h) {
  int wid = (blockIdx.x * 256 + threadIdx.x) >> 6;
  int lane = threadIdx.x & 63;
  int half = lane >> 5;
  int cp = lane & 31;
  int start = off[wid], end = off[wid + 1];
  float a0x=0.f,a0y=0.f,a1x=0.f,a1y=0.f,a2x=0.f,a2y=0.f,a3x=0.f,a3y=0.f;
  int c0=0,c1=0,c2=0,c3=0;
  int niter = (end - start + 1) >> 1;
  for (int t = 0; t < niter; t += 2) {
    int idx0 = start + 2 * t + half;
    int idx1 = idx0 + 2;
    int p0 = (idx0 < end) ? eprep[idx0] : 0x70000;
    int p1 = (idx1 < end) ? eprep[idx1] : 0x70000;
    int s0 = p0 & 0xFFFF, r0 = p0 >> 16;
    int s1 = p1 & 0xFFFF, r1 = p1 >> 16;
    unsigned u0 = *reinterpret_cast<const unsigned*>(
        &xtbf[(size_t)s0 * MBIG + H1 + (r0 << 6) + cp * 2]);
    unsigned u1 = *reinterpret_cast<const unsigned*>(
        &xtbf[(size_t)s1 * MBIG + H1 + (r1 << 6) + cp * 2]);
    float v0x = bflo(u0), v0y = bfhi(u0);
    float v1x = bflo(u1), v1y = bfhi(u1);
    a0x += (r0==0)?v0x:0.f; a0y += (r0==0)?v0y:0.f; c0 += (r0==0);
    a1x += (r0==1)?v0x:0.f; a1y += (r0==1)?v0y:0.f; c1 += (r0==1);
    a2x += (r0==2)?v0x:0.f; a2y += (r0==2)?v0y:0.f; c2 += (r0==2);
    a3x += (r0==3)?v0x:0.f; a3y += (r0==3)?v0y:0.f; c3 += (r0==3);
    a0x += (r1==0)?v1x:0.f; a0y += (r1==0)?v1y:0.f; c0 += (r1==0);
    a1x += (r1==1)?v1x:0.f; a1y += (r1==1)?v1y:0.f; c1 += (r1==1);
    a2x += (r1==2)?v1x:0.f; a2y += (r1==2)?v1y:0.f; c2 += (r1==2);
    a3x += (r1==3)?v1x:0.f; a3y += (r1==3)?v1y:0.f; c3 += (r1==3);
  }
  a0x += __shfl_xor(a0x, 32); a0y += __shfl_xor(a0y, 32);
  a1x += __shfl_xor(a1x, 32); a1y += __shfl_xor(a1y, 32);
  a2x += __shfl_xor(a2x, 32); a2y += __shfl_xor(a2y, 32);
  a3x += __shfl_xor(a3x, 32); a3y += __shfl_xor(a3y, 32);
  c0 += __shfl_xor(c0, 32); c1 += __shfl_xor(c1, 32);
  c2 += __shfl_xor(c2, 32); c3 += __shfl_xor(c3, 32);
  if (half == 0) {
    unsigned ur = *reinterpret_cast<const unsigned*>(&xtbf[(size_t)wid * MBIG + cp * 2]);
    float2 bb = *reinterpret_cast<const float2*>(&b_rgcn[cp * 2]);
    float i0 = 1.0f / (float)max(c0, 1);
    float i1 = 1.0f / (float)max(c1, 1);
    float i2 = 1.0f / (float)max(c2, 1);
    float i3 = 1.0f / (float)max(c3, 1);
    float vx = bflo(ur) + bb.x + a0x * i0 + a1x * i1 + a2x * i2 + a3x * i3;
    float vy = bfhi(ur) + bb.y + a0y * i0 + a1y * i1 + a2y * i2 + a3y * i3;
    *reinterpret_cast<float2*>(&h[(size_t)wid * H1 + cp * 2]) =
        make_float2(fmaxf(vx, 0.f), fmaxf(vy, 0.f));
  }
}

// ---- attention coefficients from bf16 g, LDS-staged ----
__global__ __launch_bounds__(256) void gat_att(const unsigned short* __restrict__ gbf,
                                               const float* __restrict__ att_src,
                                               const float* __restrict__ att_dst,
                                               float* __restrict__ a_s,
                                               float* __restrict__ a_d) {
  __shared__ float gs[64][129];
  __shared__ float asrc[HOUT], adst[HOUT];
  int t = threadIdx.x;
  if (t < HOUT) { asrc[t] = att_src[t]; adst[t] = att_dst[t]; }
  int nb = blockIdx.x * 64;
#pragma unroll
  for (int it = 0; it < 8; ++it) {
    int idx = it * 256 + t;
    int r = idx >> 5, c4 = (idx & 31) * 4;
    int gn = nb + r;
    uint2 v = make_uint2(0u, 0u);
    if (gn < N_NODES)
      v = *reinterpret_cast<const uint2*>(&gbf[(size_t)gn * HOUT + c4]);
    gs[r][c4 + 0] = bflo(v.x); gs[r][c4 + 1] = bfhi(v.x);
    gs[r][c4 + 2] = bflo(v.y); gs[r][c4 + 3] = bfhi(v.y);
  }
  __syncthreads();
  int n = t & 63, hh = t >> 6;
  float s = 0.f, d = 0.f;
#pragma unroll
  for (int k = 0; k < D_H; ++k) {
    float gv = gs[n][hh * D_H + k];
    s += gv * asrc[hh * D_H + k];
    d += gv * adst[hh * D_H + k];
  }
  if (nb + n < N_NODES) {
    a_s[(size_t)(nb + n) * 4 + hh] = s;
    a_d[(size_t)(nb + n) * 4 + hh] = d;
  }
}

// ---- init mono buffer ----
__global__ __launch_bounds__(256) void init_mono(unsigned* __restrict__ p, int count) {
  int i = blockIdx.x * 256 + threadIdx.x;
  if (i < count) p[i] = MONO_NEG_INF;
}

// ---- GAT + head fused: softmax aggregation (wave/node, grid-stride),
//      then z = leaky(o@W1+b1) via LDS W1 + shfl reduce, per-graph max pool.
//      Block: 256 thr / 4 waves; one sp flush per block. ----
constexpr int GAT_BLOCKS = 768;
constexpr int GAT_WAVES = GAT_BLOCKS * 4;
__global__ __launch_bounds__(256) void gat_fused(const unsigned short* __restrict__ gbf,
                                                 const float* __restrict__ a_s,
                                                 const float* __restrict__ a_d,
                                                 const int* __restrict__ off,
                                                 const int* __restrict__ eprep,
                                                 const float* __restrict__ b_gat,
                                                 const float* __restrict__ W1,
                                                 const float* __restrict__ b1,
                                                 const int* __restrict__ batch,
                                                 unsigned* __restrict__ p_mono) {
  __shared__ float w1s[HOUT * 16];        // W1[k][j] natural layout
  __shared__ float ob[4][HOUT];           // per-wave o row
  __shared__ unsigned sp[N_GRAPHS * 16];
  const int t = threadIdx.x;
  for (int i = t; i < HOUT * 16; i += 256) w1s[i] = W1[i];
  for (int i = t; i < N_GRAPHS * 16; i += 256) sp[i] = MONO_NEG_INF;
  __syncthreads();
  const int wv = t >> 6, lane = t & 63;
  const int hh = lane >> 4;               // head for edge phase
  const int jj = lane & 15, grp = lane >> 4;  // head-phase reuse: j, channel-group
  const int baseWave = blockIdx.x * 4 + wv;
  const int NLOOP = (N_NODES + GAT_WAVES - 1) / GAT_WAVES;
  for (int it = 0; it < NLOOP; ++it) {
    int wid = baseWave + it * GAT_WAVES;
    if (wid < N_NODES) {
      int start = off[wid], end = off[wid + 1];
      float4 ad4 = *reinterpret_cast<const float4*>(a_d + (size_t)wid * 4);
      float adh = (hh == 0) ? ad4.x : (hh == 1) ? ad4.y : (hh == 2) ? ad4.z : ad4.w;
      float ox = 0.f, oy = 0.f, den = 0.f;
      int i = start;
      for (; i + 4 <= end; i += 4) {
        int p0 = eprep[i], p1 = eprep[i + 1], p2 = eprep[i + 2], p3 = eprep[i + 3];
        int s0 = p0 & 0xFFFF, s1 = p1 & 0xFFFF, s2 = p2 & 0xFFFF, s3 = p3 & 0xFFFF;
        float as0 = a_s[(size_t)s0 * 4 + hh];
        float as1 = a_s[(size_t)s1 * 4 + hh];
        float as2 = a_s[(size_t)s2 * 4 + hh];
        float as3 = a_s[(size_t)s3 * 4 + hh];
        unsigned u0 = *reinterpret_cast<const unsigned*>(&gbf[(size_t)s0 * HOUT + lane * 2]);
        unsigned u1 = *reinterpret_cast<const unsigned*>(&gbf[(size_t)s1 * HOUT + lane * 2]);
        unsigned u2 = *reinterpret_cast<const unsigned*>(&gbf[(size_t)s2 * HOUT + lane * 2]);
        unsigned u3 = *reinterpret_cast<const unsigned*>(&gbf[(size_t)s3 * HOUT + lane * 2]);
        float e0 = as0 + adh; e0 = (e0 > 0.f) ? e0 : 0.2f * e0;
        float e1 = as1 + adh; e1 = (e1 > 0.f) ? e1 : 0.2f * e1;
        float e2 = as2 + adh; e2 = (e2 > 0.f) ? e2 : 0.2f * e2;
        float e3 = as3 + adh; e3 = (e3 > 0.f) ? e3 : 0.2f * e3;
        float x0 = __expf(e0), x1 = __expf(e1), x2 = __expf(e2), x3 = __expf(e3);
        den += x0 + x1 + x2 + x3;
        ox += x0 * bflo(u0) + x1 * bflo(u1) + x2 * bflo(u2) + x3 * bflo(u3);
        oy += x0 * bfhi(u0) + x1 * bfhi(u1) + x2 * bfhi(u2) + x3 * bfhi(u3);
      }
      for (; i < end; ++i) {
        int p = eprep[i];
        int s = p & 0xFFFF;
        float as = a_s[(size_t)s * 4 + hh];
        unsigned u = *reinterpret_cast<const unsigned*>(&gbf[(size_t)s * HOUT + lane * 2]);
        float e = as + adh; e = (e > 0.f) ? e : 0.2f * e;
        float ex = __expf(e);
        den += ex;
        ox += ex * bflo(u);
        oy += ex * bfhi(u);
      }
      float dinv = (den > 0.f) ? (1.0f / den) : 0.f;
      float2 bg = *reinterpret_cast<const float2*>(b_gat + lane * 2);
      float vx = ox * dinv + bg.x; vx = (vx > 0.f) ? vx : 0.01f * vx;
      float vy = oy * dinv + bg.y; vy = (vy > 0.f) ? vy : 0.01f * vy;
      // head: stage o row, z_j over channel-group, shfl-combine
      *reinterpret_cast<float2*>(&ob[wv][lane * 2]) = make_float2(vx, vy);
      float acc = 0.f;
#pragma unroll 8
      for (int c = grp * 32; c < grp * 32 + 32; ++c)
        acc += ob[wv][c] * w1s[c * 16 + jj];
      acc += __shfl_xor(acc, 16);
      acc += __shfl_xor(acc, 32);
      float z = acc + b1[jj];
      z = (z > 0.f) ? z : 0.01f * z;
      int b = batch[wid];
      if (lane < 16) atomicMax(&sp[b * 16 + jj], f2mono(z));
    }
  }
  __syncthreads();
  for (int i = t; i < N_GRAPHS * 16; i += 256) {
    unsigned v = sp[i];
    if (v != MONO_NEG_INF) atomicMax(p_mono + i, v);
  }
}

// ---- y = p @ W2 + b2 ----
__global__ void final_y(const unsigned* __restrict__ p_mono,
                        const float* __restrict__ W2,
                        const float* __restrict__ b2,
                        float* __restrict__ y) {
  int gr = threadIdx.x;
  if (gr >= N_GRAPHS) return;
  float acc = b2[0];
#pragma unroll
  for (int k = 0; k < 16; ++k) acc += mono2f(p_mono[gr * 16 + k]) * W2[k];
  y[gr] = acc;
}

extern "C" void kernel_launch(void* const* d_in, const int* in_sizes, int n_in,
                              void* d_out, int out_size, void* d_ws, size_t ws_size,
                              hipStream_t stream) {
  const float* x       = (const float*)d_in[0];
  const int*   eidx    = (const int*)d_in[1];
  const int*   etype   = (const int*)d_in[2];
  const int*   batch   = (const int*)d_in[3];
  const float* W_rel   = (const float*)d_in[4];
  const float* W_root  = (const float*)d_in[5];
  const float* b_rgcn  = (const float*)d_in[6];
  const float* W_gat   = (const float*)d_in[7];
  const float* att_src = (const float*)d_in[8];
  const float* att_dst = (const float*)d_in[9];
  const float* b_gat   = (const float*)d_in[10];
  const float* W1      = (const float*)d_in[11];
  const float* b1      = (const float*)d_in[12];
  const float* W2      = (const float*)d_in[13];
  const float* b2      = (const float*)d_in[14];
  float* y = (float*)d_out;

  const int* src = eidx;
  const int* dst = eidx + N_EDGES;

  float* ws = (float*)d_ws;
  const size_t OFF_XTBF= 0;           //  8,000,000 f: xt bf16 [N,320]
  const size_t OFF_GBF = 0;           //  g bf16 [N,128] (reuses xtbf)
  const size_t OFF_H   = 8000000;     //  3,200,000  h [N,64] f32
  const size_t OFF_AS  = 11200000;    //    200,000  a_src
  const size_t OFF_AD  = 11400000;    //    200,000  a_dst
  const size_t OFF_PM  = 11600000;    //        256  pool max (1024 u32)
  const size_t OFF_DEG = 11601024;    //     50,000  deg (int)
  const size_t OFF_OFFS= 11651024;    //     50,001  off (int)
  const size_t OFF_RANK= 11701040;    //    800,000  rank (int)
  const size_t OFF_EP  = 12501040;    //    800,000  eprep (int)
  const size_t OFF_BS  = 13301040;    //        196
  const size_t OFF_BB  = 13301236;    //        196
  const size_t OFF_WBH = 13301504;    //     20,480  WbigT_hi (16B aligned)
  const size_t OFF_WBL = 13321984;    //     20,480  WbigT_lo
  const size_t OFF_WGH = 13342464;    //      4,096  WgatT_hi
  const size_t OFF_WGL = 13346560;    //      4,096  WgatT_lo
  const size_t TOTAL_F = 13350656;
  if (ws_size < TOTAL_F * sizeof(float)) return;

  unsigned short* xtbf = (unsigned short*)(ws + OFF_XTBF);
  unsigned short* gbf  = (unsigned short*)(ws + OFF_GBF);
  float* h     = ws + OFF_H;
  float* a_s   = ws + OFF_AS;
  float* a_d   = ws + OFF_AD;
  unsigned* pm = (unsigned*)(ws + OFF_PM);
  int* deg     = (int*)(ws + OFF_DEG);
  int* offs    = (int*)(ws + OFF_OFFS);
  int* rank    = (int*)(ws + OFF_RANK);
  int* eprep   = (int*)(ws + OFF_EP);
  int* bsum    = (int*)(ws + OFF_BS);
  int* bbase   = (int*)(ws + OFF_BB);
  unsigned short* wbt_hi = (unsigned short*)(ws + OFF_WBH);
  unsigned short* wbt_lo = (unsigned short*)(ws + OFF_WBL);
  unsigned short* wgt_hi = (unsigned short*)(ws + OFF_WGH);
  unsigned short* wgt_lo = (unsigned short*)(ws + OFF_WGL);

  // CSR build (atomic-free fill)
  hipMemsetAsync(deg, 0, N_NODES * sizeof(int), stream);
  k_hist<<<(N_EDGES + 255) / 256, 256, 0, stream>>>(dst, deg, rank);
  k_s1<<<NBLK, 256, 0, stream>>>(deg, bsum);
  k_s2<<<1, 256, 0, stream>>>(bsum, bbase, offs);
  k_s3<<<NBLK, 256, 0, stream>>>(deg, bbase, offs);
  k_fill<<<(N_EDGES + 255) / 256, 256, 0, stream>>>(src, dst, etype, offs, rank, eprep);

  // transposed bf16 hi/lo weights
  build_wT<<<(MBIG * F_IN + HOUT * H1 + 255) / 256, 256, 0, stream>>>(
      W_root, W_rel, W_gat, wbt_hi, wbt_lo, wgt_hi, wgt_lo);

  // xt(bf16) = x @ [W_root | W_rel]
  {
    dim3 grid((N_NODES + 63) / 64, MBIG / 64);
    gemm_mfma<128><<<grid, 256, 0, stream>>>(x, wbt_hi, wbt_lo, nullptr, xtbf,
                                             N_NODES, MBIG);
  }

  // RGCN gather -> h (f32)
  rgcn_gather<<<N_NODES / 4, 256, 0, stream>>>(xtbf, offs, eprep, b_rgcn, h);

  // g(bf16) = h @ W_gat
  {
    dim3 grid((N_NODES + 63) / 64, HOUT / 64);
    gemm_mfma<64><<<grid, 256, 0, stream>>>(h, wgt_hi, wgt_lo, nullptr, gbf,
                                            N_NODES, HOUT);
  }

  // attention coefficients
  gat_att<<<(N_NODES + 63) / 64, 256, 0, stream>>>(gbf, att_src, att_dst, a_s, a_d);

  // fused GAT aggregation + head + per-graph max pool
  init_mono<<<(N_GRAPHS * 16 + 255) / 256, 256, 0, stream>>>(pm, N_GRAPHS * 16);
  gat_fused<<<GAT_BLOCKS, 256, 0, stream>>>(gbf, a_s, a_d, offs, eprep, b_gat,
                                            W1, b1, batch, pm);

  // y = p @ W2 + b2
  final_y<<<1, 64, 0, stream>>>(pm, W2, b2, y);
}

// Round 8
// 224.413 us; speedup vs baseline: 10.9174x; 1.2039x over previous
//
#include <hip/hip_runtime.h>
#include <hip/hip_bf16.h>

constexpr int N_NODES = 50000;
constexpr int N_EDGES = 800000;
constexpr int F_IN = 128;
constexpr int H1 = 64;
constexpr int HEADS = 4;
constexpr int D_H = 32;
constexpr int HOUT = HEADS * D_H;       // 128
constexpr int N_REL = 4;
constexpr int N_GRAPHS = 64;
constexpr int MBIG = H1 * (1 + N_REL);  // 320
constexpr int NBLK = (N_NODES + 255) / 256;  // 196

typedef __attribute__((ext_vector_type(8))) short bf16x8;
typedef __attribute__((ext_vector_type(4))) float f32x4;

// ---- monotonic float<->uint for atomicMax on floats ----
__device__ __forceinline__ unsigned f2mono(float f) {
  unsigned u = __float_as_uint(f);
  return (u & 0x80000000u) ? ~u : (u | 0x80000000u);
}
__device__ __forceinline__ float mono2f(unsigned m) {
  unsigned u = (m & 0x80000000u) ? (m & 0x7FFFFFFFu) : ~m;
  return __uint_as_float(u);
}
constexpr unsigned MONO_NEG_INF = 0x007FFFFFu;

// ---- bf16 helpers ----
__device__ __forceinline__ unsigned short f2bf(float f) {
  unsigned u = __float_as_uint(f);
  unsigned r = (u + 0x7FFFu + ((u >> 16) & 1u)) >> 16;  // RNE
  return (unsigned short)r;
}
__device__ __forceinline__ float bf2f(unsigned short h) {
  return __uint_as_float((unsigned)h << 16);
}
__device__ __forceinline__ float bflo(unsigned u) { return __uint_as_float(u << 16); }
__device__ __forceinline__ float bfhi(unsigned u) { return __uint_as_float(u & 0xFFFF0000u); }

// ---- build transposed bf16 hi/lo weights ----
__global__ __launch_bounds__(256) void build_wT(const float* __restrict__ W_root,
                                                const float* __restrict__ W_rel,
                                                const float* __restrict__ W_gat,
                                                unsigned short* __restrict__ WbT_hi,
                                                unsigned short* __restrict__ WbT_lo,
                                                unsigned short* __restrict__ WgT_hi,
                                                unsigned short* __restrict__ WgT_lo) {
  int i = blockIdx.x * 256 + threadIdx.x;
  if (i < MBIG * F_IN) {               // WbigT[c][k]
    int c = i / F_IN, k = i % F_IN;
    float w = (c < H1) ? W_root[k * H1 + c]
                       : W_rel[((size_t)(((c - H1) >> 6) * F_IN + k)) * H1 + ((c - H1) & 63)];
    unsigned short hi = f2bf(w);
    WbT_hi[i] = hi;
    WbT_lo[i] = f2bf(w - bf2f(hi));
  } else {
    int j = i - MBIG * F_IN;
    if (j < HOUT * H1) {               // WgatT[c][k]
      int c = j / H1, k = j % H1;
      float w = W_gat[k * HOUT + c];
      unsigned short hi = f2bf(w);
      WgT_hi[j] = hi;
      WgT_lo[j] = f2bf(w - bf2f(hi));
    }
  }
}

// ---- split-bf16 MFMA GEMM, 2D grid: block = 64 rows x 64 cols ----
template <int K>
__global__ __launch_bounds__(256) void gemm_mfma(const float* __restrict__ A,
                                                 const unsigned short* __restrict__ BT_hi,
                                                 const unsigned short* __restrict__ BT_lo,
                                                 float* __restrict__ C,
                                                 unsigned short* __restrict__ Cbf,
                                                 int N, int M) {
  constexpr int Kp = K + 8;
  __shared__ unsigned short Ahi[64 * Kp];
  __shared__ unsigned short Alo[64 * Kp];
  const int tid = threadIdx.x;
  const int rowBase = blockIdx.x * 64;
  const int colBase = blockIdx.y * 64;
  constexpr int KQ = K >> 2;
  constexpr int slots = 64 * KQ;
  for (int s = tid; s < slots; s += 256) {
    int r = s / KQ, c4 = (s % KQ) * 4;
    int gr = rowBase + r;
    float4 v = make_float4(0.f, 0.f, 0.f, 0.f);
    if (gr < N) v = *reinterpret_cast<const float4*>(&A[(size_t)gr * K + c4]);
    ushort4 hi, lo;
    hi.x = f2bf(v.x); lo.x = f2bf(v.x - bf2f(hi.x));
    hi.y = f2bf(v.y); lo.y = f2bf(v.y - bf2f(hi.y));
    hi.z = f2bf(v.z); lo.z = f2bf(v.z - bf2f(hi.z));
    hi.w = f2bf(v.w); lo.w = f2bf(v.w - bf2f(hi.w));
    *reinterpret_cast<ushort4*>(&Ahi[r * Kp + c4]) = hi;
    *reinterpret_cast<ushort4*>(&Alo[r * Kp + c4]) = lo;
  }
  __syncthreads();
  const int wv = tid >> 6, lane = tid & 63;
  const int wr = (wv >> 1) * 32, wc = (wv & 1) * 32;
  const int lrow = lane & 15, lkc = lane >> 4;
  f32x4 acc[2][2] = {};
#pragma unroll
  for (int ks = 0; ks < K; ks += 32) {
    bf16x8 ah[2], al[2], bh[2], bl[2];
#pragma unroll
    for (int fr = 0; fr < 2; ++fr) {
      int r = wr + fr * 16 + lrow;
      ah[fr] = *reinterpret_cast<const bf16x8*>(&Ahi[r * Kp + ks + lkc * 8]);
      al[fr] = *reinterpret_cast<const bf16x8*>(&Alo[r * Kp + ks + lkc * 8]);
    }
#pragma unroll
    for (int fc = 0; fc < 2; ++fc) {
      int c = colBase + wc + fc * 16 + lrow;
      bh[fc] = *reinterpret_cast<const bf16x8*>(&BT_hi[(size_t)c * K + ks + lkc * 8]);
      bl[fc] = *reinterpret_cast<const bf16x8*>(&BT_lo[(size_t)c * K + ks + lkc * 8]);
    }
#pragma unroll
    for (int fr = 0; fr < 2; ++fr)
#pragma unroll
      for (int fc = 0; fc < 2; ++fc) {
        acc[fr][fc] = __builtin_amdgcn_mfma_f32_16x16x32_bf16(ah[fr], bh[fc], acc[fr][fc], 0, 0, 0);
        acc[fr][fc] = __builtin_amdgcn_mfma_f32_16x16x32_bf16(ah[fr], bl[fc], acc[fr][fc], 0, 0, 0);
        acc[fr][fc] = __builtin_amdgcn_mfma_f32_16x16x32_bf16(al[fr], bh[fc], acc[fr][fc], 0, 0, 0);
      }
  }
#pragma unroll
  for (int fr = 0; fr < 2; ++fr) {
#pragma unroll
    for (int i = 0; i < 4; ++i) {
      int row = rowBase + wr + fr * 16 + lkc * 4 + i;
      if (row < N) {
#pragma unroll
        for (int fc = 0; fc < 2; ++fc) {
          int col = colBase + wc + fc * 16 + lrow;
          float v = acc[fr][fc][i];
          if (C) C[(size_t)row * M + col] = v;
          if (Cbf) Cbf[(size_t)row * M + col] = f2bf(v);
        }
      }
    }
  }
}

// ---- CSR build: histogram of dst + per-edge rank (coalesced store) ----
__global__ __launch_bounds__(256) void k_hist(const int* __restrict__ dst,
                                              int* __restrict__ deg,
                                              int* __restrict__ rank) {
  int e = blockIdx.x * 256 + threadIdx.x;
  if (e < N_EDGES) rank[e] = atomicAdd(&deg[dst[e]], 1);
}

// ---- scan stage 1: per-block sums ----
__global__ __launch_bounds__(256) void k_s1(const int* __restrict__ deg,
                                            int* __restrict__ bsum) {
  __shared__ int ss[256];
  int t = threadIdx.x;
  int i = blockIdx.x * 256 + t;
  ss[t] = (i < N_NODES) ? deg[i] : 0;
  __syncthreads();
  for (int d = 128; d > 0; d >>= 1) {
    if (t < d) ss[t] += ss[t + d];
    __syncthreads();
  }
  if (t == 0) bsum[blockIdx.x] = ss[0];
}

// ---- scan stage 2: exclusive scan of block sums ----
__global__ __launch_bounds__(256) void k_s2(const int* __restrict__ bsum,
                                            int* __restrict__ bbase,
                                            int* __restrict__ off) {
  __shared__ int ss[256];
  int t = threadIdx.x;
  int v = (t < NBLK) ? bsum[t] : 0;
  ss[t] = v;
  __syncthreads();
  for (int d = 1; d < 256; d <<= 1) {
    int u = (t >= d) ? ss[t - d] : 0;
    __syncthreads();
    ss[t] += u;
    __syncthreads();
  }
  if (t < NBLK) bbase[t] = ss[t] - v;
  if (t == NBLK - 1) off[N_NODES] = ss[t];
}

// ---- scan stage 3: block-local scan + base ----
__global__ __launch_bounds__(256) void k_s3(const int* __restrict__ deg,
                                            const int* __restrict__ bbase,
                                            int* __restrict__ off) {
  __shared__ int ss[256];
  int t = threadIdx.x;
  int i = blockIdx.x * 256 + t;
  int v = (i < N_NODES) ? deg[i] : 0;
  ss[t] = v;
  __syncthreads();
  for (int d = 1; d < 256; d <<= 1) {
    int u = (t >= d) ? ss[t - d] : 0;
    __syncthreads();
    ss[t] += u;
    __syncthreads();
  }
  if (i < N_NODES) off[i] = bbase[blockIdx.x] + ss[t] - v;
}

// ---- CSR fill: atomic-free — pos = off[dst] + rank; scatter store ----
__global__ __launch_bounds__(256) void k_fill(const int* __restrict__ src,
                                              const int* __restrict__ dst,
                                              const int* __restrict__ etype,
                                              const int* __restrict__ off,
                                              const int* __restrict__ rank,
                                              int* __restrict__ eprep) {
  int e = blockIdx.x * 256 + threadIdx.x;
  if (e >= N_EDGES) return;
  int pos = off[dst[e]] + rank[e];
  eprep[pos] = src[e] | (etype[e] << 16);
}

// ---- RGCN: gather from bf16 xt; wave/node; 2 edges/iter, x2 unroll ----
__global__ __launch_bounds__(256) void rgcn_gather(const unsigned short* __restrict__ xtbf,
                                                   const int* __restrict__ off,
                                                   const int* __restrict__ eprep,
                                                   const float* __restrict__ b_rgcn,
                                                   float* __restrict__ h) {
  int wid = (blockIdx.x * 256 + threadIdx.x) >> 6;
  int lane = threadIdx.x & 63;
  int half = lane >> 5;
  int cp = lane & 31;
  int start = off[wid], end = off[wid + 1];
  float a0x=0.f,a0y=0.f,a1x=0.f,a1y=0.f,a2x=0.f,a2y=0.f,a3x=0.f,a3y=0.f;
  int c0=0,c1=0,c2=0,c3=0;
  int niter = (end - start + 1) >> 1;
  for (int t = 0; t < niter; t += 2) {
    int idx0 = start + 2 * t + half;
    int idx1 = idx0 + 2;
    int p0 = (idx0 < end) ? eprep[idx0] : 0x70000;
    int p1 = (idx1 < end) ? eprep[idx1] : 0x70000;
    int s0 = p0 & 0xFFFF, r0 = p0 >> 16;
    int s1 = p1 & 0xFFFF, r1 = p1 >> 16;
    unsigned u0 = *reinterpret_cast<const unsigned*>(
        &xtbf[(size_t)s0 * MBIG + H1 + (r0 << 6) + cp * 2]);
    unsigned u1 = *reinterpret_cast<const unsigned*>(
        &xtbf[(size_t)s1 * MBIG + H1 + (r1 << 6) + cp * 2]);
    float v0x = bflo(u0), v0y = bfhi(u0);
    float v1x = bflo(u1), v1y = bfhi(u1);
    a0x += (r0==0)?v0x:0.f; a0y += (r0==0)?v0y:0.f; c0 += (r0==0);
    a1x += (r0==1)?v0x:0.f; a1y += (r0==1)?v0y:0.f; c1 += (r0==1);
    a2x += (r0==2)?v0x:0.f; a2y += (r0==2)?v0y:0.f; c2 += (r0==2);
    a3x += (r0==3)?v0x:0.f; a3y += (r0==3)?v0y:0.f; c3 += (r0==3);
    a0x += (r1==0)?v1x:0.f; a0y += (r1==0)?v1y:0.f; c0 += (r1==0);
    a1x += (r1==1)?v1x:0.f; a1y += (r1==1)?v1y:0.f; c1 += (r1==1);
    a2x += (r1==2)?v1x:0.f; a2y += (r1==2)?v1y:0.f; c2 += (r1==2);
    a3x += (r1==3)?v1x:0.f; a3y += (r1==3)?v1y:0.f; c3 += (r1==3);
  }
  a0x += __shfl_xor(a0x, 32); a0y += __shfl_xor(a0y, 32);
  a1x += __shfl_xor(a1x, 32); a1y += __shfl_xor(a1y, 32);
  a2x += __shfl_xor(a2x, 32); a2y += __shfl_xor(a2y, 32);
  a3x += __shfl_xor(a3x, 32); a3y += __shfl_xor(a3y, 32);
  c0 += __shfl_xor(c0, 32); c1 += __shfl_xor(c1, 32);
  c2 += __shfl_xor(c2, 32); c3 += __shfl_xor(c3, 32);
  if (half == 0) {
    unsigned ur = *reinterpret_cast<const unsigned*>(&xtbf[(size_t)wid * MBIG + cp * 2]);
    float2 bb = *reinterpret_cast<const float2*>(&b_rgcn[cp * 2]);
    float i0 = 1.0f / (float)max(c0, 1);
    float i1 = 1.0f / (float)max(c1, 1);
    float i2 = 1.0f / (float)max(c2, 1);
    float i3 = 1.0f / (float)max(c3, 1);
    float vx = bflo(ur) + bb.x + a0x * i0 + a1x * i1 + a2x * i2 + a3x * i3;
    float vy = bfhi(ur) + bb.y + a0y * i0 + a1y * i1 + a2y * i2 + a3y * i3;
    *reinterpret_cast<float2*>(&h[(size_t)wid * H1 + cp * 2]) =
        make_float2(fmaxf(vx, 0.f), fmaxf(vy, 0.f));
  }
}

// ---- attention coefficients from bf16 g, LDS-staged ----
__global__ __launch_bounds__(256) void gat_att(const unsigned short* __restrict__ gbf,
                                               const float* __restrict__ att_src,
                                               const float* __restrict__ att_dst,
                                               float* __restrict__ a_s,
                                               float* __restrict__ a_d) {
  __shared__ float gs[64][129];
  __shared__ float asrc[HOUT], adst[HOUT];
  int t = threadIdx.x;
  if (t < HOUT) { asrc[t] = att_src[t]; adst[t] = att_dst[t]; }
  int nb = blockIdx.x * 64;
#pragma unroll
  for (int it = 0; it < 8; ++it) {
    int idx = it * 256 + t;
    int r = idx >> 5, c4 = (idx & 31) * 4;
    int gn = nb + r;
    uint2 v = make_uint2(0u, 0u);
    if (gn < N_NODES)
      v = *reinterpret_cast<const uint2*>(&gbf[(size_t)gn * HOUT + c4]);
    gs[r][c4 + 0] = bflo(v.x); gs[r][c4 + 1] = bfhi(v.x);
    gs[r][c4 + 2] = bflo(v.y); gs[r][c4 + 3] = bfhi(v.y);
  }
  __syncthreads();
  int n = t & 63, hh = t >> 6;
  float s = 0.f, d = 0.f;
#pragma unroll
  for (int k = 0; k < D_H; ++k) {
    float gv = gs[n][hh * D_H + k];
    s += gv * asrc[hh * D_H + k];
    d += gv * adst[hh * D_H + k];
  }
  if (nb + n < N_NODES) {
    a_s[(size_t)(nb + n) * 4 + hh] = s;
    a_d[(size_t)(nb + n) * 4 + hh] = d;
  }
}

// ---- init mono buffer ----
__global__ __launch_bounds__(256) void init_mono(unsigned* __restrict__ p, int count) {
  int i = blockIdx.x * 256 + threadIdx.x;
  if (i < count) p[i] = MONO_NEG_INF;
}

// ---- GAT + head fused: wave/node over a CONTIGUOUS per-wave range,
//      full-occupancy grid (8 blocks/CU); z via LDS W1 (2-way-max banks)
//      + shfl reduce; per-graph max pool with one sp flush per block. ----
constexpr int GAT_BLOCKS = 2048;
constexpr int GAT_WAVES = GAT_BLOCKS * 4;   // 8192
__global__ __launch_bounds__(256) void gat_fused(const unsigned short* __restrict__ gbf,
                                                 const float* __restrict__ a_s,
                                                 const float* __restrict__ a_d,
                                                 const int* __restrict__ off,
                                                 const int* __restrict__ eprep,
                                                 const float* __restrict__ b_gat,
                                                 const float* __restrict__ W1,
                                                 const float* __restrict__ b1,
                                                 const int* __restrict__ batch,
                                                 unsigned* __restrict__ p_mono) {
  __shared__ float w1s[HOUT * 16];        // W1[k][j]
  __shared__ float ob[4][HOUT];           // per-wave o row
  __shared__ unsigned sp[N_GRAPHS * 16];
  const int t = threadIdx.x;
  for (int i = t; i < HOUT * 16; i += 256) w1s[i] = W1[i];
  for (int i = t; i < N_GRAPHS * 16; i += 256) sp[i] = MONO_NEG_INF;
  __syncthreads();
  const int wv = t >> 6, lane = t & 63;
  const int hh = lane >> 4;               // head for edge phase
  const int jj = lane & 15, grp = lane >> 4;
  // contiguous per-wave node range (bijective q/r split)
  const int w = blockIdx.x * 4 + wv;
  const int q = N_NODES / GAT_WAVES;      // 6
  const int r = N_NODES % GAT_WAVES;      // 824
  const int nbeg = w * q + ((w < r) ? w : r);
  const int ncnt = q + ((w < r) ? 1 : 0);
  for (int wid = nbeg; wid < nbeg + ncnt; ++wid) {
    int start = off[wid], end = off[wid + 1];
    float4 ad4 = *reinterpret_cast<const float4*>(a_d + (size_t)wid * 4);
    float adh = (hh == 0) ? ad4.x : (hh == 1) ? ad4.y : (hh == 2) ? ad4.z : ad4.w;
    float ox = 0.f, oy = 0.f, den = 0.f;
    int i = start;
    for (; i + 4 <= end; i += 4) {
      int p0 = eprep[i], p1 = eprep[i + 1], p2 = eprep[i + 2], p3 = eprep[i + 3];
      int s0 = p0 & 0xFFFF, s1 = p1 & 0xFFFF, s2 = p2 & 0xFFFF, s3 = p3 & 0xFFFF;
      float as0 = a_s[(size_t)s0 * 4 + hh];
      float as1 = a_s[(size_t)s1 * 4 + hh];
      float as2 = a_s[(size_t)s2 * 4 + hh];
      float as3 = a_s[(size_t)s3 * 4 + hh];
      unsigned u0 = *reinterpret_cast<const unsigned*>(&gbf[(size_t)s0 * HOUT + lane * 2]);
      unsigned u1 = *reinterpret_cast<const unsigned*>(&gbf[(size_t)s1 * HOUT + lane * 2]);
      unsigned u2 = *reinterpret_cast<const unsigned*>(&gbf[(size_t)s2 * HOUT + lane * 2]);
      unsigned u3 = *reinterpret_cast<const unsigned*>(&gbf[(size_t)s3 * HOUT + lane * 2]);
      float e0 = as0 + adh; e0 = (e0 > 0.f) ? e0 : 0.2f * e0;
      float e1 = as1 + adh; e1 = (e1 > 0.f) ? e1 : 0.2f * e1;
      float e2 = as2 + adh; e2 = (e2 > 0.f) ? e2 : 0.2f * e2;
      float e3 = as3 + adh; e3 = (e3 > 0.f) ? e3 : 0.2f * e3;
      float x0 = __expf(e0), x1 = __expf(e1), x2 = __expf(e2), x3 = __expf(e3);
      den += x0 + x1 + x2 + x3;
      ox += x0 * bflo(u0) + x1 * bflo(u1) + x2 * bflo(u2) + x3 * bflo(u3);
      oy += x0 * bfhi(u0) + x1 * bfhi(u1) + x2 * bfhi(u2) + x3 * bfhi(u3);
    }
    for (; i < end; ++i) {
      int p = eprep[i];
      int s = p & 0xFFFF;
      float as = a_s[(size_t)s * 4 + hh];
      unsigned u = *reinterpret_cast<const unsigned*>(&gbf[(size_t)s * HOUT + lane * 2]);
      float e = as + adh; e = (e > 0.f) ? e : 0.2f * e;
      float ex = __expf(e);
      den += ex;
      ox += ex * bflo(u);
      oy += ex * bfhi(u);
    }
    float dinv = (den > 0.f) ? (1.0f / den) : 0.f;
    float2 bg = *reinterpret_cast<const float2*>(b_gat + lane * 2);
    float vx = ox * dinv + bg.x; vx = (vx > 0.f) ? vx : 0.01f * vx;
    float vy = oy * dinv + bg.y; vy = (vy > 0.f) ? vy : 0.01f * vy;
    // head: stage o row, z_j over interleaved channels (bank-friendly)
    *reinterpret_cast<float2*>(&ob[wv][lane * 2]) = make_float2(vx, vy);
    float acc = 0.f;
#pragma unroll 8
    for (int i2 = 0; i2 < 32; ++i2) {
      int c = grp + 4 * i2;
      acc += ob[wv][c] * w1s[c * 16 + jj];
    }
    acc += __shfl_xor(acc, 16);
    acc += __shfl_xor(acc, 32);
    float z = acc + b1[jj];
    z = (z > 0.f) ? z : 0.01f * z;
    int b = batch[wid];
    if (lane < 16) atomicMax(&sp[b * 16 + jj], f2mono(z));
  }
  __syncthreads();
  for (int i = t; i < N_GRAPHS * 16; i += 256) {
    unsigned v = sp[i];
    if (v != MONO_NEG_INF) atomicMax(p_mono + i, v);
  }
}

// ---- y = p @ W2 + b2 ----
__global__ void final_y(const unsigned* __restrict__ p_mono,
                        const float* __restrict__ W2,
                        const float* __restrict__ b2,
                        float* __restrict__ y) {
  int gr = threadIdx.x;
  if (gr >= N_GRAPHS) return;
  float acc = b2[0];
#pragma unroll
  for (int k = 0; k < 16; ++k) acc += mono2f(p_mono[gr * 16 + k]) * W2[k];
  y[gr] = acc;
}

extern "C" void kernel_launch(void* const* d_in, const int* in_sizes, int n_in,
                              void* d_out, int out_size, void* d_ws, size_t ws_size,
                              hipStream_t stream) {
  const float* x       = (const float*)d_in[0];
  const int*   eidx    = (const int*)d_in[1];
  const int*   etype   = (const int*)d_in[2];
  const int*   batch   = (const int*)d_in[3];
  const float* W_rel   = (const float*)d_in[4];
  const float* W_root  = (const float*)d_in[5];
  const float* b_rgcn  = (const float*)d_in[6];
  const float* W_gat   = (const float*)d_in[7];
  const float* att_src = (const float*)d_in[8];
  const float* att_dst = (const float*)d_in[9];
  const float* b_gat   = (const float*)d_in[10];
  const float* W1      = (const float*)d_in[11];
  const float* b1      = (const float*)d_in[12];
  const float* W2      = (const float*)d_in[13];
  const float* b2      = (const float*)d_in[14];
  float* y = (float*)d_out;

  const int* src = eidx;
  const int* dst = eidx + N_EDGES;

  float* ws = (float*)d_ws;
  const size_t OFF_XTBF= 0;           //  8,000,000 f: xt bf16 [N,320]
  const size_t OFF_GBF = 0;           //  g bf16 [N,128] (reuses xtbf)
  const size_t OFF_H   = 8000000;     //  3,200,000  h [N,64] f32
  const size_t OFF_AS  = 11200000;    //    200,000  a_src
  const size_t OFF_AD  = 11400000;    //    200,000  a_dst
  const size_t OFF_PM  = 11600000;    //        256  pool max (1024 u32)
  const size_t OFF_DEG = 11601024;    //     50,000  deg (int)
  const size_t OFF_OFFS= 11651024;    //     50,001  off (int)
  const size_t OFF_RANK= 11701040;    //    800,000  rank (int)
  const size_t OFF_EP  = 12501040;    //    800,000  eprep (int)
  const size_t OFF_BS  = 13301040;    //        196
  const size_t OFF_BB  = 13301236;    //        196
  const size_t OFF_WBH = 13301504;    //     20,480  WbigT_hi
  const size_t OFF_WBL = 13321984;    //     20,480  WbigT_lo
  const size_t OFF_WGH = 13342464;    //      4,096  WgatT_hi
  const size_t OFF_WGL = 13346560;    //      4,096  WgatT_lo
  const size_t TOTAL_F = 13350656;
  if (ws_size < TOTAL_F * sizeof(float)) return;

  unsigned short* xtbf = (unsigned short*)(ws + OFF_XTBF);
  unsigned short* gbf  = (unsigned short*)(ws + OFF_GBF);
  float* h     = ws + OFF_H;
  float* a_s   = ws + OFF_AS;
  float* a_d   = ws + OFF_AD;
  unsigned* pm = (unsigned*)(ws + OFF_PM);
  int* deg     = (int*)(ws + OFF_DEG);
  int* offs    = (int*)(ws + OFF_OFFS);
  int* rank    = (int*)(ws + OFF_RANK);
  int* eprep   = (int*)(ws + OFF_EP);
  int* bsum    = (int*)(ws + OFF_BS);
  int* bbase   = (int*)(ws + OFF_BB);
  unsigned short* wbt_hi = (unsigned short*)(ws + OFF_WBH);
  unsigned short* wbt_lo = (unsigned short*)(ws + OFF_WBL);
  unsigned short* wgt_hi = (unsigned short*)(ws + OFF_WGH);
  unsigned short* wgt_lo = (unsigned short*)(ws + OFF_WGL);

  // CSR build (atomic-free fill)
  hipMemsetAsync(deg, 0, N_NODES * sizeof(int), stream);
  k_hist<<<(N_EDGES + 255) / 256, 256, 0, stream>>>(dst, deg, rank);
  k_s1<<<NBLK, 256, 0, stream>>>(deg, bsum);
  k_s2<<<1, 256, 0, stream>>>(bsum, bbase, offs);
  k_s3<<<NBLK, 256, 0, stream>>>(deg, bbase, offs);
  k_fill<<<(N_EDGES + 255) / 256, 256, 0, stream>>>(src, dst, etype, offs, rank, eprep);

  // transposed bf16 hi/lo weights
  build_wT<<<(MBIG * F_IN + HOUT * H1 + 255) / 256, 256, 0, stream>>>(
      W_root, W_rel, W_gat, wbt_hi, wbt_lo, wgt_hi, wgt_lo);

  // xt(bf16) = x @ [W_root | W_rel]
  {
    dim3 grid((N_NODES + 63) / 64, MBIG / 64);
    gemm_mfma<128><<<grid, 256, 0, stream>>>(x, wbt_hi, wbt_lo, nullptr, xtbf,
                                             N_NODES, MBIG);
  }

  // RGCN gather -> h (f32)
  rgcn_gather<<<N_NODES / 4, 256, 0, stream>>>(xtbf, offs, eprep, b_rgcn, h);

  // g(bf16) = h @ W_gat
  {
    dim3 grid((N_NODES + 63) / 64, HOUT / 64);
    gemm_mfma<64><<<grid, 256, 0, stream>>>(h, wgt_hi, wgt_lo, nullptr, gbf,
                                            N_NODES, HOUT);
  }

  // attention coefficients
  gat_att<<<(N_NODES + 63) / 64, 256, 0, stream>>>(gbf, att_src, att_dst, a_s, a_d);

  // fused GAT aggregation + head + per-graph max pool
  init_mono<<<(N_GRAPHS * 16 + 255) / 256, 256, 0, stream>>>(pm, N_GRAPHS * 16);
  gat_fused<<<GAT_BLOCKS, 256, 0, stream>>>(gbf, a_s, a_d, offs, eprep, b_gat,
                                            W1, b1, batch, pm);

  // y = p @ W2 + b2
  final_y<<<1, 64, 0, stream>>>(pm, W2, b2, y);
}